// Round 1
// baseline (1240.807 us; speedup 1.0000x reference)
//
#include <hip/hip_runtime.h>
#include <hip/hip_bf16.h>

// Problem constants
// B=2, S=2048, D=2048, H=16, I=8192, HD=512; M = B*S = 4096.

typedef __bf16 bf16x8 __attribute__((ext_vector_type(8)));
typedef float f32x4 __attribute__((ext_vector_type(4)));

__device__ __forceinline__ unsigned short f2bf(float f) {
    union { float f; unsigned int u; } x; x.f = f;
    unsigned int r = x.u + 0x7fffu + ((x.u >> 16) & 1u);  // RNE
    return (unsigned short)(r >> 16);
}
__device__ __forceinline__ float bf2f(unsigned short b) {
    union { unsigned int u; float f; } x; x.u = ((unsigned int)b) << 16;
    return x.f;
}

__device__ __forceinline__ void gload_lds16(const void* g, void* l) {
    __builtin_amdgcn_global_load_lds((const __attribute__((address_space(1))) void*)g,
                                     (__attribute__((address_space(3))) void*)l,
                                     16, 0, 0);
}

// Stage a 128-row x 64-col bf16 tile from global (row-major, leading dim ld elems)
// into LDS, linear layout [128][64], with st-style XOR swizzle applied by
// pre-swizzling the per-lane global source chunk (rule #21: linear dest,
// inverse-swizzled source; reads use frag() below with the matching XOR).
__device__ __forceinline__ void stage(unsigned short* lds, const unsigned short* g,
                                      int ld, int wave, int lane) {
    int rsub = lane >> 3;          // 0..7 row within 8-row group
    int j    = lane & 7;           // physical 16B chunk within row
    int jsw  = (j ^ rsub) << 3;    // swizzled source element offset (chunk ^ (row&7))
    const unsigned short* src = g + (size_t)(wave * 32 + rsub) * ld + jsw;
    unsigned short* dst = lds + (wave * 32) * 64;
#pragma unroll
    for (int c = 0; c < 4; ++c) {
        gload_lds16((const void*)(src + (size_t)c * 8 * ld), (void*)(dst + c * 8 * 64));
    }
}

// Read an 8-element K-contiguous bf16 fragment from a swizzled [128][64] LDS tile.
__device__ __forceinline__ bf16x8 frag(const unsigned short* lds, int row, int k) {
    int byte = ((row * 64 + k) * 2) ^ ((row & 7) << 4);
    return *(const bf16x8*)((const char*)lds + byte);
}

// ---------------- prep kernels ----------------

// straight f32 -> bf16, n divisible by 1024*... (grid*256*4 == n exactly)
__global__ void conv_kernel(const float* __restrict__ in, unsigned short* __restrict__ out) {
    size_t i = ((size_t)blockIdx.x * 256 + threadIdx.x) * 4;
    float4 v = *(const float4*)(in + i);
    ushort4 o; o.x = f2bf(v.x); o.y = f2bf(v.y); o.z = f2bf(v.z); o.w = f2bf(v.w);
    *(ushort4*)(out + i) = o;
}

// transpose + convert: in R x C f32 -> out C x R bf16. 64x64 tiles, 256 thr.
__global__ void tconv_kernel(const float* __restrict__ in, unsigned short* __restrict__ out,
                             int R, int C) {
    __shared__ float tile[64][65];
    int nbc = C >> 6;
    int bc = blockIdx.x % nbc, br = blockIdx.x / nbc;
    int r0 = br * 64, c0 = bc * 64;
    int t = threadIdx.x;
#pragma unroll
    for (int i = 0; i < 4; ++i) {
        int idx = i * 256 + t;
        int r = idx >> 4, c4 = (idx & 15) * 4;
        float4 v = *(const float4*)(in + (size_t)(r0 + r) * C + c0 + c4);
        tile[r][c4] = v.x; tile[r][c4 + 1] = v.y; tile[r][c4 + 2] = v.z; tile[r][c4 + 3] = v.w;
    }
    __syncthreads();
#pragma unroll
    for (int i = 0; i < 4; ++i) {
        int idx = i * 256 + t;
        int c = idx >> 4, r4 = (idx & 15) * 4;
        ushort4 o;
        o.x = f2bf(tile[r4][c]); o.y = f2bf(tile[r4 + 1][c]);
        o.z = f2bf(tile[r4 + 2][c]); o.w = f2bf(tile[r4 + 3][c]);
        *(ushort4*)(out + (size_t)(c0 + c) * R + r0 + r4) = o;
    }
}

// ---------------- GEMM 1: gate/up fused ----------------
// C_g = xb * WgT^T, C_u = xb * WuT^T ; h = silu(g)*u -> hh (MxN) and hhT (B,I,S)
__global__ void __launch_bounds__(256) gemm_gateup(
    const unsigned short* __restrict__ xb,    // 4096 x 2048
    const unsigned short* __restrict__ WgT,   // 8192 x 2048
    const unsigned short* __restrict__ WuT,   // 8192 x 2048
    unsigned short* __restrict__ hh,          // 4096 x 8192
    unsigned short* __restrict__ hhT)         // (2*8192) x 2048
{
    const int K = 2048, N = 8192;
    __shared__ unsigned short As[128 * 64], Bgs[128 * 64], Bus[128 * 64];
    int bid = blockIdx.x;
    int nt = bid & 63, mt = bid >> 6;
    int tid = threadIdx.x, wave = tid >> 6, lane = tid & 63;
    int wm = wave >> 1, wn = wave & 1;
    f32x4 accg[4][4] = {};
    f32x4 accu[4][4] = {};
    const unsigned short* Ab = xb + (size_t)(mt * 128) * K;
    const unsigned short* Bg = WgT + (size_t)(nt * 128) * K;
    const unsigned short* Bu = WuT + (size_t)(nt * 128) * K;
    for (int k0 = 0; k0 < K; k0 += 64) {
        stage(As, Ab + k0, K, wave, lane);
        stage(Bgs, Bg + k0, K, wave, lane);
        stage(Bus, Bu + k0, K, wave, lane);
        __syncthreads();
#pragma unroll
        for (int ki = 0; ki < 2; ++ki) {
            int kk = ki * 32 + ((lane >> 4) << 3);
            bf16x8 af[4], bgf[4], buf_[4];
#pragma unroll
            for (int mi = 0; mi < 4; ++mi) af[mi] = frag(As, wm * 64 + mi * 16 + (lane & 15), kk);
#pragma unroll
            for (int ni = 0; ni < 4; ++ni) {
                int r = wn * 64 + ni * 16 + (lane & 15);
                bgf[ni] = frag(Bgs, r, kk);
                buf_[ni] = frag(Bus, r, kk);
            }
#pragma unroll
            for (int mi = 0; mi < 4; ++mi)
#pragma unroll
                for (int ni = 0; ni < 4; ++ni) {
                    accg[mi][ni] = __builtin_amdgcn_mfma_f32_16x16x32_bf16(af[mi], bgf[ni], accg[mi][ni], 0, 0, 0);
                    accu[mi][ni] = __builtin_amdgcn_mfma_f32_16x16x32_bf16(af[mi], buf_[ni], accu[mi][ni], 0, 0, 0);
                }
        }
        __syncthreads();
    }
    int m_off = mt * 128 + wm * 64;
    int n_off = nt * 128 + wn * 64;
#pragma unroll
    for (int mi = 0; mi < 4; ++mi)
#pragma unroll
        for (int ni = 0; ni < 4; ++ni) {
            int mbase = m_off + mi * 16 + ((lane >> 4) << 2);
            int n = n_off + ni * 16 + (lane & 15);
            ushort4 hv;
#pragma unroll
            for (int r = 0; r < 4; ++r) {
                float g = accg[mi][ni][r], u = accu[mi][ni][r];
                float h = g / (1.f + __expf(-g)) * u;
                unsigned short hb = f2bf(h);
                ((unsigned short*)&hv)[r] = hb;
                hh[(size_t)(mbase + r) * N + n] = hb;
            }
            int b = mbase >> 11, s = mbase & 2047;
            *(ushort4*)(hhT + ((size_t)b * N + n) * 2048 + s) = hv;
        }
}

// ---------------- GEMM 2: agg + GIN mix ----------------
__global__ void __launch_bounds__(256) gemm_agg(
    const float* __restrict__ adj,            // (B*H) x S x S f32
    const unsigned short* __restrict__ hhT,   // (B*I) x S
    const unsigned short* __restrict__ hh,    // (B*S) x I
    const float* __restrict__ eps, const float* __restrict__ alpha,
    unsigned short* __restrict__ hcomb)       // (B*S) x I
{
    const int S = 2048, HD = 512, I = 8192;
    __shared__ unsigned short As[128 * 64], Bs[128 * 64];
    int bid = blockIdx.x;
    int pair = bid >> 6;           // b*16 + h
    int tile = bid & 63;
    int mt = tile >> 2, nt = tile & 3;
    int b = pair >> 4, h = pair & 15;
    int tid = threadIdx.x, wave = tid >> 6, lane = tid & 63;
    int wm = wave >> 1, wn = wave & 1;
    f32x4 acc[4][4] = {};
    const float* Ab = adj + ((size_t)pair * S + mt * 128) * S;
    const unsigned short* Bb = hhT + ((size_t)(b * I + h * HD + nt * 128)) * S;
    for (int k0 = 0; k0 < S; k0 += 64) {
        // reg-stage A with f32->bf16 conversion, swizzled ds_write_b64
#pragma unroll
        for (int c = 0; c < 8; ++c) {
            int idx = c * 256 + tid;
            int row = idx >> 4, e = (idx & 15) << 2;
            float4 v = *(const float4*)(Ab + (size_t)row * S + k0 + e);
            ushort4 o; o.x = f2bf(v.x); o.y = f2bf(v.y); o.z = f2bf(v.z); o.w = f2bf(v.w);
            int byte = ((row * 64 + e) * 2) ^ ((row & 7) << 4);
            *(ushort4*)((char*)As + byte) = o;
        }
        stage(Bs, Bb + k0, S, wave, lane);
        __syncthreads();
#pragma unroll
        for (int ki = 0; ki < 2; ++ki) {
            int kk = ki * 32 + ((lane >> 4) << 3);
            bf16x8 af[4], bfv[4];
#pragma unroll
            for (int mi = 0; mi < 4; ++mi) af[mi] = frag(As, wm * 64 + mi * 16 + (lane & 15), kk);
#pragma unroll
            for (int ni = 0; ni < 4; ++ni) bfv[ni] = frag(Bs, wn * 64 + ni * 16 + (lane & 15), kk);
#pragma unroll
            for (int mi = 0; mi < 4; ++mi)
#pragma unroll
                for (int ni = 0; ni < 4; ++ni)
                    acc[mi][ni] = __builtin_amdgcn_mfma_f32_16x16x32_bf16(af[mi], bfv[ni], acc[mi][ni], 0, 0, 0);
        }
        __syncthreads();
    }
    float e1 = 1.f + eps[h];
    float a1 = alpha[h];
    int m_off = mt * 128 + wm * 64, n_off = nt * 128 + wn * 64;
#pragma unroll
    for (int mi = 0; mi < 4; ++mi)
#pragma unroll
        for (int ni = 0; ni < 4; ++ni) {
            int sbase = m_off + mi * 16 + ((lane >> 4) << 2);
            int d = n_off + ni * 16 + (lane & 15);
            size_t col = (size_t)h * HD + d;
#pragma unroll
            for (int r = 0; r < 4; ++r) {
                size_t off = ((size_t)b * S + sbase + r) * I + col;
                float hv = bf2f(hh[off]);
                float gin = e1 * hv + a1 * acc[mi][ni][r];
                hcomb[off] = f2bf(gin);
            }
        }
}

// ---------------- GEMM 3: final projection ----------------
__global__ void __launch_bounds__(256) gemm_out(
    const unsigned short* __restrict__ hcomb, // 4096 x 8192
    const unsigned short* __restrict__ WdT,   // 2048 x 8192
    float* __restrict__ out)                  // 4096 x 2048
{
    const int K = 8192, N = 2048;
    __shared__ unsigned short As[128 * 64], Bs[128 * 64];
    int bid = blockIdx.x;
    int nt = bid & 15, mt = bid >> 4;
    int tid = threadIdx.x, wave = tid >> 6, lane = tid & 63;
    int wm = wave >> 1, wn = wave & 1;
    f32x4 acc[4][4] = {};
    const unsigned short* Ab = hcomb + (size_t)(mt * 128) * K;
    const unsigned short* Bb = WdT + (size_t)(nt * 128) * K;
    for (int k0 = 0; k0 < K; k0 += 64) {
        stage(As, Ab + k0, K, wave, lane);
        stage(Bs, Bb + k0, K, wave, lane);
        __syncthreads();
#pragma unroll
        for (int ki = 0; ki < 2; ++ki) {
            int kk = ki * 32 + ((lane >> 4) << 3);
            bf16x8 af[4], bfv[4];
#pragma unroll
            for (int mi = 0; mi < 4; ++mi) af[mi] = frag(As, wm * 64 + mi * 16 + (lane & 15), kk);
#pragma unroll
            for (int ni = 0; ni < 4; ++ni) bfv[ni] = frag(Bs, wn * 64 + ni * 16 + (lane & 15), kk);
#pragma unroll
            for (int mi = 0; mi < 4; ++mi)
#pragma unroll
                for (int ni = 0; ni < 4; ++ni)
                    acc[mi][ni] = __builtin_amdgcn_mfma_f32_16x16x32_bf16(af[mi], bfv[ni], acc[mi][ni], 0, 0, 0);
        }
        __syncthreads();
    }
    int m_off = mt * 128 + wm * 64, n_off = nt * 128 + wn * 64;
#pragma unroll
    for (int mi = 0; mi < 4; ++mi)
#pragma unroll
        for (int ni = 0; ni < 4; ++ni) {
            int mbase = m_off + mi * 16 + ((lane >> 4) << 2);
            int n = n_off + ni * 16 + (lane & 15);
#pragma unroll
            for (int r = 0; r < 4; ++r)
                out[(size_t)(mbase + r) * N + n] = acc[mi][ni][r];
        }
}

extern "C" void kernel_launch(void* const* d_in, const int* in_sizes, int n_in,
                              void* d_out, int out_size, void* d_ws, size_t ws_size,
                              hipStream_t stream) {
    const float* x     = (const float*)d_in[0];
    const float* adj   = (const float*)d_in[1];
    const float* Wg    = (const float*)d_in[2];
    const float* Wu    = (const float*)d_in[3];
    const float* Wd    = (const float*)d_in[4];
    const float* eps   = (const float*)d_in[5];
    const float* alpha = (const float*)d_in[6];
    float* out = (float*)d_out;

    // workspace layout (bf16 elems), total ~304 MiB
    unsigned short* ws    = (unsigned short*)d_ws;
    unsigned short* xb    = ws;                               // 4096*2048
    unsigned short* WgT   = xb + (size_t)4096 * 2048;         // 8192*2048
    unsigned short* WuT   = WgT + (size_t)8192 * 2048;        // 8192*2048
    unsigned short* WdT   = WuT + (size_t)8192 * 2048;        // 2048*8192
    unsigned short* hh    = WdT + (size_t)2048 * 8192;        // 4096*8192
    unsigned short* hhT   = hh + (size_t)4096 * 8192;         // 16384*2048
    unsigned short* hcomb = hhT + (size_t)16384 * 2048;       // 4096*8192

    conv_kernel<<<8192, 256, 0, stream>>>(x, xb);                         // 4096x2048
    tconv_kernel<<<4096, 256, 0, stream>>>(Wg, WgT, 2048, 8192);
    tconv_kernel<<<4096, 256, 0, stream>>>(Wu, WuT, 2048, 8192);
    tconv_kernel<<<4096, 256, 0, stream>>>(Wd, WdT, 8192, 2048);
    gemm_gateup<<<32 * 64, 256, 0, stream>>>(xb, WgT, WuT, hh, hhT);
    gemm_agg<<<32 * 16 * 4, 256, 0, stream>>>(adj, hhT, hh, eps, alpha, hcomb);
    gemm_out<<<32 * 16, 256, 0, stream>>>(hcomb, WdT, out);
}

// Round 2
// 988.758 us; speedup vs baseline: 1.2549x; 1.2549x over previous
//
#include <hip/hip_runtime.h>
#include <hip/hip_bf16.h>

// Problem constants
// B=2, S=2048, D=2048, H=16, I=8192, HD=512; M = B*S = 4096.

typedef __bf16 bf16x8 __attribute__((ext_vector_type(8)));
typedef float f32x4 __attribute__((ext_vector_type(4)));

__device__ __forceinline__ unsigned short f2bf(float f) {
    union { float f; unsigned int u; } x; x.f = f;
    unsigned int r = x.u + 0x7fffu + ((x.u >> 16) & 1u);  // RNE
    return (unsigned short)(r >> 16);
}
__device__ __forceinline__ float bf2f(unsigned short b) {
    union { unsigned int u; float f; } x; x.u = ((unsigned int)b) << 16;
    return x.f;
}

__device__ __forceinline__ void gload_lds16(const void* g, void* l) {
    __builtin_amdgcn_global_load_lds((const __attribute__((address_space(1))) void*)g,
                                     (__attribute__((address_space(3))) void*)l,
                                     16, 0, 0);
}

// Stage a 128-row x 64-col bf16 tile from global (row-major, leading dim ld elems)
// into LDS, linear layout [128][64], swizzle via pre-swizzled global source chunk.
__device__ __forceinline__ void stage(unsigned short* lds, const unsigned short* g,
                                      int ld, int wave, int lane) {
    int rsub = lane >> 3;          // 0..7 row within 8-row group
    int j    = lane & 7;           // physical 16B chunk within row
    int jsw  = (j ^ rsub) << 3;    // swizzled source element offset
    const unsigned short* src = g + (size_t)(wave * 32 + rsub) * ld + jsw;
    unsigned short* dst = lds + (wave * 32) * 64;
#pragma unroll
    for (int c = 0; c < 4; ++c) {
        gload_lds16((const void*)(src + (size_t)c * 8 * ld), (void*)(dst + c * 8 * 64));
    }
}

// Read an 8-element K-contiguous bf16 fragment from a swizzled [128][64] LDS tile.
__device__ __forceinline__ bf16x8 frag(const unsigned short* lds, int row, int k) {
    int byte = ((row * 64 + k) * 2) ^ ((row & 7) << 4);
    return *(const bf16x8*)((const char*)lds + byte);
}

// ---------------- prep kernels ----------------

__global__ void conv_kernel(const float* __restrict__ in, unsigned short* __restrict__ out) {
    size_t i = ((size_t)blockIdx.x * 256 + threadIdx.x) * 4;
    float4 v = *(const float4*)(in + i);
    ushort4 o; o.x = f2bf(v.x); o.y = f2bf(v.y); o.z = f2bf(v.z); o.w = f2bf(v.w);
    *(ushort4*)(out + i) = o;
}

// transpose + convert: in R x C f32 -> out C x R bf16. 64x64 tiles, 256 thr.
__global__ void tconv_kernel(const float* __restrict__ in, unsigned short* __restrict__ out,
                             int R, int C) {
    __shared__ float tile[64][65];
    int nbc = C >> 6;
    int bc = blockIdx.x % nbc, br = blockIdx.x / nbc;
    int r0 = br * 64, c0 = bc * 64;
    int t = threadIdx.x;
#pragma unroll
    for (int i = 0; i < 4; ++i) {
        int idx = i * 256 + t;
        int r = idx >> 4, c4 = (idx & 15) * 4;
        float4 v = *(const float4*)(in + (size_t)(r0 + r) * C + c0 + c4);
        tile[r][c4] = v.x; tile[r][c4 + 1] = v.y; tile[r][c4 + 2] = v.z; tile[r][c4 + 3] = v.w;
    }
    __syncthreads();
#pragma unroll
    for (int i = 0; i < 4; ++i) {
        int idx = i * 256 + t;
        int c = idx >> 4, r4 = (idx & 15) * 4;
        ushort4 o;
        o.x = f2bf(tile[r4][c]); o.y = f2bf(tile[r4 + 1][c]);
        o.z = f2bf(tile[r4 + 2][c]); o.w = f2bf(tile[r4 + 3][c]);
        *(ushort4*)(out + (size_t)(c0 + c) * R + r0 + r4) = o;
    }
}

// ---------------- GEMM 1: gate/up fused ----------------
__global__ void __launch_bounds__(256) gemm_gateup(
    const unsigned short* __restrict__ xb,    // 4096 x 2048
    const unsigned short* __restrict__ WgT,   // 8192 x 2048
    const unsigned short* __restrict__ WuT,   // 8192 x 2048
    unsigned short* __restrict__ hh,          // 4096 x 8192
    unsigned short* __restrict__ hhT)         // (2*8192) x 2048
{
    const int K = 2048, N = 8192;
    __shared__ unsigned short As[128 * 64], Bgs[128 * 64], Bus[128 * 64];
    int bid = blockIdx.x;
    int nt = bid & 63, mt = bid >> 6;
    int tid = threadIdx.x, wave = tid >> 6, lane = tid & 63;
    int wm = wave >> 1, wn = wave & 1;
    f32x4 accg[4][4] = {};
    f32x4 accu[4][4] = {};
    const unsigned short* Ab = xb + (size_t)(mt * 128) * K;
    const unsigned short* Bg = WgT + (size_t)(nt * 128) * K;
    const unsigned short* Bu = WuT + (size_t)(nt * 128) * K;
    for (int k0 = 0; k0 < K; k0 += 64) {
        stage(As, Ab + k0, K, wave, lane);
        stage(Bgs, Bg + k0, K, wave, lane);
        stage(Bus, Bu + k0, K, wave, lane);
        __syncthreads();
#pragma unroll
        for (int ki = 0; ki < 2; ++ki) {
            int kk = ki * 32 + ((lane >> 4) << 3);
            bf16x8 af[4], bgf[4], buf_[4];
#pragma unroll
            for (int mi = 0; mi < 4; ++mi) af[mi] = frag(As, wm * 64 + mi * 16 + (lane & 15), kk);
#pragma unroll
            for (int ni = 0; ni < 4; ++ni) {
                int r = wn * 64 + ni * 16 + (lane & 15);
                bgf[ni] = frag(Bgs, r, kk);
                buf_[ni] = frag(Bus, r, kk);
            }
#pragma unroll
            for (int mi = 0; mi < 4; ++mi)
#pragma unroll
                for (int ni = 0; ni < 4; ++ni) {
                    accg[mi][ni] = __builtin_amdgcn_mfma_f32_16x16x32_bf16(af[mi], bgf[ni], accg[mi][ni], 0, 0, 0);
                    accu[mi][ni] = __builtin_amdgcn_mfma_f32_16x16x32_bf16(af[mi], buf_[ni], accu[mi][ni], 0, 0, 0);
                }
        }
        __syncthreads();
    }
    int m_off = mt * 128 + wm * 64;
    int n_off = nt * 128 + wn * 64;
#pragma unroll
    for (int mi = 0; mi < 4; ++mi)
#pragma unroll
        for (int ni = 0; ni < 4; ++ni) {
            int mbase = m_off + mi * 16 + ((lane >> 4) << 2);
            int n = n_off + ni * 16 + (lane & 15);
            ushort4 hv;
#pragma unroll
            for (int r = 0; r < 4; ++r) {
                float g = accg[mi][ni][r], u = accu[mi][ni][r];
                float h = g / (1.f + __expf(-g)) * u;
                unsigned short hb = f2bf(h);
                ((unsigned short*)&hv)[r] = hb;
                hh[(size_t)(mbase + r) * N + n] = hb;
            }
            int b = mbase >> 11, s = mbase & 2047;
            *(ushort4*)(hhT + ((size_t)b * N + n) * 2048 + s) = hv;
        }
}

// ---------------- GEMM 2: agg + GIN mix (v2) ----------------
// Per (b,h): C[128 x 512] block, adjacency streamed ONCE in f32.
// 8 waves (2M x 4N), wave tile 64x128, BK=32, single padded LDS buffer,
// T14 reg-prefetch of both operands.
__global__ void __launch_bounds__(512) gemm_agg2(
    const float* __restrict__ adj,            // (B*H=32) x S x S f32
    const unsigned short* __restrict__ hhT,   // (B*I) x S bf16
    const unsigned short* __restrict__ hh,    // (B*S) x I bf16
    const float* __restrict__ eps, const float* __restrict__ alpha,
    unsigned short* __restrict__ hcomb)       // (B*S) x I bf16
{
    const int S = 2048, HD = 512, I = 8192;
    // padded rows: 32 data elems + 8 pad = 40 elems = 80 bytes -> 2-way-free banks
    __shared__ unsigned short As[128 * 40];   // 10 KB
    __shared__ unsigned short Bs[512 * 40];   // 40 KB
    int bid = (int)blockIdx.x;
    // bijective XCD chunk swizzle: nwg=512, 64 consecutive logical blocks per XCD
    int lb = (bid & 7) * 64 + (bid >> 3);
    int pair = lb >> 4;            // b*16 + h
    int mt = lb & 15;
    int b = pair >> 4, h = pair & 15;
    int tid = threadIdx.x;
    int lane = tid & 63;
    int wave = tid >> 6;
    int wm = wave >> 2, wn = wave & 3;        // 2 x 4 wave grid
    f32x4 acc[4][8] = {};

    const float* Ab = adj + ((size_t)pair * S + (size_t)mt * 128) * S;
    const unsigned short* Bb = hhT + ((size_t)b * I + (size_t)h * HD) * (size_t)S;

    // prefetch registers
    float4 pa0, pa1;
    int4 pb0, pb1, pb2, pb3;
    // A: 128x32 f32 -> thread covers 8 f32 (2 float4): idx=p*512+tid, row=idx>>3, col=(idx&7)*4
    int a_row0 = tid >> 3, a_c = (tid & 7) << 2;
    // B: 512x32 bf16 -> 4 passes, row=p*128+(tid>>2), chunk=(tid&3)*8 elems
    int b_row0 = tid >> 2, b_ch = (tid & 3) << 3;

#define AGG_LOAD(K0)                                                              \
    do {                                                                          \
        pa0 = *(const float4*)(Ab + (size_t)a_row0 * S + (K0) + a_c);             \
        pa1 = *(const float4*)(Ab + (size_t)(a_row0 + 64) * S + (K0) + a_c);      \
        pb0 = *(const int4*)(Bb + (size_t)b_row0 * S + (K0) + b_ch);              \
        pb1 = *(const int4*)(Bb + (size_t)(b_row0 + 128) * S + (K0) + b_ch);      \
        pb2 = *(const int4*)(Bb + (size_t)(b_row0 + 256) * S + (K0) + b_ch);      \
        pb3 = *(const int4*)(Bb + (size_t)(b_row0 + 384) * S + (K0) + b_ch);      \
    } while (0)

#define AGG_WRITE()                                                               \
    do {                                                                          \
        ushort4 o0, o1;                                                           \
        o0.x = f2bf(pa0.x); o0.y = f2bf(pa0.y); o0.z = f2bf(pa0.z); o0.w = f2bf(pa0.w); \
        o1.x = f2bf(pa1.x); o1.y = f2bf(pa1.y); o1.z = f2bf(pa1.z); o1.w = f2bf(pa1.w); \
        *(ushort4*)((char*)As + a_row0 * 80 + a_c * 2) = o0;                      \
        *(ushort4*)((char*)As + (a_row0 + 64) * 80 + a_c * 2) = o1;               \
        *(int4*)((char*)Bs + b_row0 * 80 + b_ch * 2) = pb0;                       \
        *(int4*)((char*)Bs + (b_row0 + 128) * 80 + b_ch * 2) = pb1;               \
        *(int4*)((char*)Bs + (b_row0 + 256) * 80 + b_ch * 2) = pb2;               \
        *(int4*)((char*)Bs + (b_row0 + 384) * 80 + b_ch * 2) = pb3;               \
    } while (0)

    AGG_LOAD(0);
    AGG_WRITE();
    __syncthreads();

    int lrow = lane & 15;
    int koff2 = ((lane >> 4) << 3) * 2;       // byte offset of k-slice
    const char* aptr = (const char*)As + (wm * 64 + lrow) * 80 + koff2;
    const char* bptr = (const char*)Bs + (wn * 128 + lrow) * 80 + koff2;

    for (int step = 0; step < 64; ++step) {
        bool more = (step + 1) < 64;
        if (more) AGG_LOAD((step + 1) * 32);
        bf16x8 af[4], bfv[8];
#pragma unroll
        for (int mi = 0; mi < 4; ++mi) af[mi] = *(const bf16x8*)(aptr + mi * 16 * 80);
#pragma unroll
        for (int ni = 0; ni < 8; ++ni) bfv[ni] = *(const bf16x8*)(bptr + ni * 16 * 80);
#pragma unroll
        for (int mi = 0; mi < 4; ++mi)
#pragma unroll
            for (int ni = 0; ni < 8; ++ni)
                acc[mi][ni] = __builtin_amdgcn_mfma_f32_16x16x32_bf16(af[mi], bfv[ni], acc[mi][ni], 0, 0, 0);
        __syncthreads();
        if (more) {
            AGG_WRITE();
            __syncthreads();
        }
    }
#undef AGG_LOAD
#undef AGG_WRITE

    float e1 = 1.f + eps[h];
    float a1 = alpha[h];
    int s_base = mt * 128 + wm * 64;
    int d_base = wn * 128;
#pragma unroll
    for (int mi = 0; mi < 4; ++mi)
#pragma unroll
        for (int ni = 0; ni < 8; ++ni) {
            int sb = s_base + mi * 16 + ((lane >> 4) << 2);
            int d = d_base + ni * 16 + (lane & 15);
#pragma unroll
            for (int r = 0; r < 4; ++r) {
                size_t off = ((size_t)(b * S + sb + r)) * I + (size_t)h * HD + d;
                float hv = bf2f(hh[off]);
                hcomb[off] = f2bf(e1 * hv + a1 * acc[mi][ni][r]);
            }
        }
}

// ---------------- GEMM 3: final projection ----------------
__global__ void __launch_bounds__(256) gemm_out(
    const unsigned short* __restrict__ hcomb, // 4096 x 8192
    const unsigned short* __restrict__ WdT,   // 2048 x 8192
    float* __restrict__ out)                  // 4096 x 2048
{
    const int K = 8192, N = 2048;
    __shared__ unsigned short As[128 * 64], Bs[128 * 64];
    int bid = blockIdx.x;
    int nt = bid & 15, mt = bid >> 4;
    int tid = threadIdx.x, wave = tid >> 6, lane = tid & 63;
    int wm = wave >> 1, wn = wave & 1;
    f32x4 acc[4][4] = {};
    const unsigned short* Ab = hcomb + (size_t)(mt * 128) * K;
    const unsigned short* Bb = WdT + (size_t)(nt * 128) * K;
    for (int k0 = 0; k0 < K; k0 += 64) {
        stage(As, Ab + k0, K, wave, lane);
        stage(Bs, Bb + k0, K, wave, lane);
        __syncthreads();
#pragma unroll
        for (int ki = 0; ki < 2; ++ki) {
            int kk = ki * 32 + ((lane >> 4) << 3);
            bf16x8 af[4], bfv[4];
#pragma unroll
            for (int mi = 0; mi < 4; ++mi) af[mi] = frag(As, wm * 64 + mi * 16 + (lane & 15), kk);
#pragma unroll
            for (int ni = 0; ni < 4; ++ni) bfv[ni] = frag(Bs, wn * 64 + ni * 16 + (lane & 15), kk);
#pragma unroll
            for (int mi = 0; mi < 4; ++mi)
#pragma unroll
                for (int ni = 0; ni < 4; ++ni)
                    acc[mi][ni] = __builtin_amdgcn_mfma_f32_16x16x32_bf16(af[mi], bfv[ni], acc[mi][ni], 0, 0, 0);
        }
        __syncthreads();
    }
    int m_off = mt * 128 + wm * 64, n_off = nt * 128 + wn * 64;
#pragma unroll
    for (int mi = 0; mi < 4; ++mi)
#pragma unroll
        for (int ni = 0; ni < 4; ++ni) {
            int mbase = m_off + mi * 16 + ((lane >> 4) << 2);
            int n = n_off + ni * 16 + (lane & 15);
#pragma unroll
            for (int r = 0; r < 4; ++r)
                out[(size_t)(mbase + r) * N + n] = acc[mi][ni][r];
        }
}

extern "C" void kernel_launch(void* const* d_in, const int* in_sizes, int n_in,
                              void* d_out, int out_size, void* d_ws, size_t ws_size,
                              hipStream_t stream) {
    const float* x     = (const float*)d_in[0];
    const float* adj   = (const float*)d_in[1];
    const float* Wg    = (const float*)d_in[2];
    const float* Wu    = (const float*)d_in[3];
    const float* Wd    = (const float*)d_in[4];
    const float* eps   = (const float*)d_in[5];
    const float* alpha = (const float*)d_in[6];
    float* out = (float*)d_out;

    unsigned short* ws    = (unsigned short*)d_ws;
    unsigned short* xb    = ws;                               // 4096*2048
    unsigned short* WgT   = xb + (size_t)4096 * 2048;         // 8192*2048
    unsigned short* WuT   = WgT + (size_t)8192 * 2048;        // 8192*2048
    unsigned short* WdT   = WuT + (size_t)8192 * 2048;        // 2048*8192
    unsigned short* hh    = WdT + (size_t)2048 * 8192;        // 4096*8192
    unsigned short* hhT   = hh + (size_t)4096 * 8192;         // 16384*2048
    unsigned short* hcomb = hhT + (size_t)16384 * 2048;       // 4096*8192

    conv_kernel<<<8192, 256, 0, stream>>>(x, xb);
    tconv_kernel<<<4096, 256, 0, stream>>>(Wg, WgT, 2048, 8192);
    tconv_kernel<<<4096, 256, 0, stream>>>(Wu, WuT, 2048, 8192);
    tconv_kernel<<<4096, 256, 0, stream>>>(Wd, WdT, 8192, 2048);
    gemm_gateup<<<32 * 64, 256, 0, stream>>>(xb, WgT, WuT, hh, hhT);
    gemm_agg2<<<512, 512, 0, stream>>>(adj, hhT, hh, eps, alpha, hcomb);
    gemm_out<<<32 * 16, 256, 0, stream>>>(hcomb, WdT, out);
}

// Round 3
// 826.901 us; speedup vs baseline: 1.5006x; 1.1957x over previous
//
#include <hip/hip_runtime.h>
#include <hip/hip_bf16.h>

// B=2, S=2048, D=2048, H=16, I=8192, HD=512; M = B*S = 4096.

typedef __bf16 bf16x8 __attribute__((ext_vector_type(8)));
typedef float f32x4 __attribute__((ext_vector_type(4)));

__device__ __forceinline__ unsigned short f2bf(float f) {
    union { float f; unsigned int u; } x; x.f = f;
    unsigned int r = x.u + 0x7fffu + ((x.u >> 16) & 1u);  // RNE
    return (unsigned short)(r >> 16);
}
__device__ __forceinline__ float bf2f(unsigned short b) {
    union { unsigned int u; float f; } x; x.u = ((unsigned int)b) << 16;
    return x.f;
}

__device__ __forceinline__ void gload_lds16(const void* g, void* l) {
    __builtin_amdgcn_global_load_lds((const __attribute__((address_space(1))) void*)g,
                                     (__attribute__((address_space(3))) void*)l,
                                     16, 0, 0);
}

// ---- legacy 128x64 stage/frag (used by agg2 / gemm_out) ----
__device__ __forceinline__ void stage(unsigned short* lds, const unsigned short* g,
                                      int ld, int wave, int lane) {
    int rsub = lane >> 3;
    int j    = lane & 7;
    int jsw  = (j ^ rsub) << 3;
    const unsigned short* src = g + (size_t)(wave * 32 + rsub) * ld + jsw;
    unsigned short* dst = lds + (wave * 32) * 64;
#pragma unroll
    for (int c = 0; c < 4; ++c) {
        gload_lds16((const void*)(src + (size_t)c * 8 * ld), (void*)(dst + c * 8 * 64));
    }
}
__device__ __forceinline__ bf16x8 frag(const unsigned short* lds, int row, int k) {
    int byte = ((row * 64 + k) * 2) ^ ((row & 7) << 4);
    return *(const bf16x8*)((const char*)lds + byte);
}

// ---------------- prep kernels ----------------

__global__ void conv_kernel(const float* __restrict__ in, unsigned short* __restrict__ out) {
    size_t i = ((size_t)blockIdx.x * 256 + threadIdx.x) * 4;
    float4 v = *(const float4*)(in + i);
    ushort4 o; o.x = f2bf(v.x); o.y = f2bf(v.y); o.z = f2bf(v.z); o.w = f2bf(v.w);
    *(ushort4*)(out + i) = o;
}

__global__ void tconv_kernel(const float* __restrict__ in, unsigned short* __restrict__ out,
                             int R, int C) {
    __shared__ float tile[64][65];
    int nbc = C >> 6;
    int bc = blockIdx.x % nbc, br = blockIdx.x / nbc;
    int r0 = br * 64, c0 = bc * 64;
    int t = threadIdx.x;
#pragma unroll
    for (int i = 0; i < 4; ++i) {
        int idx = i * 256 + t;
        int r = idx >> 4, c4 = (idx & 15) * 4;
        float4 v = *(const float4*)(in + (size_t)(r0 + r) * C + c0 + c4);
        tile[r][c4] = v.x; tile[r][c4 + 1] = v.y; tile[r][c4 + 2] = v.z; tile[r][c4 + 3] = v.w;
    }
    __syncthreads();
#pragma unroll
    for (int i = 0; i < 4; ++i) {
        int idx = i * 256 + t;
        int c = idx >> 4, r4 = (idx & 15) * 4;
        ushort4 o;
        o.x = f2bf(tile[r4][c]); o.y = f2bf(tile[r4 + 1][c]);
        o.z = f2bf(tile[r4 + 2][c]); o.w = f2bf(tile[r4 + 3][c]);
        *(ushort4*)(out + (size_t)(c0 + c) * R + r0 + r4) = o;
    }
}

// ---------------- 256x256 deep-pipelined GEMM for gate / up ----------------
// A: 4096 x 2048 bf16 row-major; Bop: 8192 x 2048 bf16 row-major (W^T form).
// BK=32, 4 LDS buffers, loads run 2 K-tiles ahead, tile-top vmcnt(4), 1 barrier/tile.
// LDS per buffer: A-part 8192 ushorts ([128 prow][64]: prow r pairs rows {r, r+128};
// chunks 0-3 = low row, 4-7 = high row, XOR-swizzled by (prow&7)), B-part same.
// EPI=0: store gate in frag-linear layout (coalesced). EPI=1: read gate, h=silu(g)*u,
// write hh (row-major) + hhT (transposed).
template<int EPI>
__global__ void __launch_bounds__(512, 2) gemm256(
    const unsigned short* __restrict__ Ag,
    const unsigned short* __restrict__ Bg,
    const unsigned short* __restrict__ gbuf_c,
    unsigned short* __restrict__ gbuf,
    unsigned short* __restrict__ hh,
    unsigned short* __restrict__ hhT)
{
    const int K = 2048;
    __shared__ unsigned short LDS[4][16384];   // 128 KB total
    int bid = (int)blockIdx.x;
    int lb = (bid & 7) * 64 + (bid >> 3);      // bijective XCD chunk swizzle (512 = 8*64)
    int nt = lb & 31, mt = lb >> 5;
    int tid = threadIdx.x, lane = tid & 63, wave = tid >> 6;
    int wm = wave >> 2, wn = wave & 3;         // 2 x 4 wave grid, wave tile 128x64
    int l15 = lane & 15, l4 = lane >> 4;

    f32x4 acc[8][4] = {};

    // staging source mapping (per lane): lds slot (prow, jphys=lane&7) gets data for
    // jlog = jphys ^ (prow&7) -> row = prow + 128*(jlog>=4), kchunk = jlog&3
    int jl = (lane & 7) ^ (lane >> 3);
    int prow0 = wave * 16 + (lane >> 3);
    int row0 = prow0 + ((jl & 4) << 5);
    int cc = (jl & 3) << 3;
    const unsigned short* srcA0 = Ag + (size_t)(mt * 256 + row0) * K + cc;
    const unsigned short* srcA1 = srcA0 + (size_t)8 * K;   // call c=1: prow += 8
    const unsigned short* srcB0 = Bg + (size_t)(nt * 256 + row0) * K + cc;
    const unsigned short* srcB1 = srcB0 + (size_t)8 * K;

    // frag read byte bases
    int cA = l15 * 128 + (((l4 + wm * 4) ^ (l15 & 7)) << 4);
    int cB = ((wn & 1) * 64 + l15) * 128 + (((l4 + ((wn >> 1) << 2)) ^ (l15 & 7)) << 4);

#define STAGE_A(t_) do { char* d_ = (char*)&LDS[(t_) & 3][0] + wave * 2048;              \
        gload_lds16((const void*)(srcA0 + (size_t)(t_) * 32), (void*)d_);                \
        gload_lds16((const void*)(srcA1 + (size_t)(t_) * 32), (void*)(d_ + 1024)); } while (0)
#define STAGE_B(t_) do { char* d_ = (char*)&LDS[(t_) & 3][8192] + wave * 2048;           \
        gload_lds16((const void*)(srcB0 + (size_t)(t_) * 32), (void*)d_);                \
        gload_lds16((const void*)(srcB1 + (size_t)(t_) * 32), (void*)(d_ + 1024)); } while (0)

    // prologue: tiles 0 and 1 in flight (8 loads/thread)
    STAGE_A(0); STAGE_B(0);
    STAGE_A(1); STAGE_B(1);

    for (int t = 0; t < 64; ++t) {
        // guarantee: all loads except the newest 4 (tile t+1's) have landed => tile t ready
        asm volatile("s_waitcnt vmcnt(4)" ::: "memory");
        __builtin_amdgcn_s_barrier();
        const char* Abase = (const char*)&LDS[t & 3][0];
        const char* Bbase = Abase + 16384;
        bool more = (t + 2) < 64;
        // ---- phase 0: rows wm*128 + [0,64) ----
        if (more) STAGE_A(t + 2);
        bf16x8 bf[4], af[4];
#pragma unroll
        for (int ni = 0; ni < 4; ++ni) bf[ni] = *(const bf16x8*)(Bbase + cB + ni * 2048);
#pragma unroll
        for (int mi = 0; mi < 4; ++mi) af[mi] = *(const bf16x8*)(Abase + cA + mi * 2048);
        __builtin_amdgcn_s_setprio(1);
#pragma unroll
        for (int mi = 0; mi < 4; ++mi)
#pragma unroll
            for (int ni = 0; ni < 4; ++ni)
                acc[mi][ni] = __builtin_amdgcn_mfma_f32_16x16x32_bf16(af[mi], bf[ni], acc[mi][ni], 0, 0, 0);
        __builtin_amdgcn_s_setprio(0);
        // ---- phase 1: rows wm*128 + [64,128) ----
        if (more) STAGE_B(t + 2);
#pragma unroll
        for (int mi = 0; mi < 4; ++mi) af[mi] = *(const bf16x8*)(Abase + cA + 8192 + mi * 2048);
        __builtin_amdgcn_s_setprio(1);
#pragma unroll
        for (int mi = 0; mi < 4; ++mi)
#pragma unroll
            for (int ni = 0; ni < 4; ++ni)
                acc[4 + mi][ni] = __builtin_amdgcn_mfma_f32_16x16x32_bf16(af[mi], bf[ni], acc[4 + mi][ni], 0, 0, 0);
        __builtin_amdgcn_s_setprio(0);
    }
#undef STAGE_A
#undef STAGE_B

    // ---------------- epilogue ----------------
    if (EPI == 0) {
        // frag-linear, perfectly coalesced: frag f of block lb at g4[(lb*32+f)*512 + tid]
        ushort4* g4 = (ushort4*)gbuf;
        size_t base = ((size_t)lb * 32) * 512 + tid;
#pragma unroll
        for (int a = 0; a < 8; ++a)
#pragma unroll
            for (int ni = 0; ni < 4; ++ni) {
                f32x4 v = acc[a][ni];
                ushort4 o;
                o.x = f2bf(v[0]); o.y = f2bf(v[1]); o.z = f2bf(v[2]); o.w = f2bf(v[3]);
                g4[base + (size_t)(a * 4 + ni) * 512] = o;
            }
    } else {
        const ushort4* g4 = (const ushort4*)gbuf_c;
        size_t base = ((size_t)lb * 32) * 512 + tid;
        int rowb = mt * 256 + wm * 128 + l4 * 4;
        int colb = nt * 256 + wn * 64 + l15;
        int b = mt >> 3;
#pragma unroll
        for (int a = 0; a < 8; ++a)
#pragma unroll
            for (int ni = 0; ni < 4; ++ni) {
                ushort4 gq = g4[base + (size_t)(a * 4 + ni) * 512];
                int row = rowb + a * 16;
                int n = colb + ni * 16;
                ushort4 hv;
#pragma unroll
                for (int r = 0; r < 4; ++r) {
                    float gv = bf2f(((const unsigned short*)&gq)[r]);
                    float u = acc[a][ni][r];
                    float h = gv / (1.f + __expf(-gv)) * u;
                    unsigned short hb = f2bf(h);
                    ((unsigned short*)&hv)[r] = hb;
                    hh[(size_t)(row + r) * 8192 + n] = hb;
                }
                *(ushort4*)(hhT + ((size_t)b * 8192 + n) * 2048 + (row & 2047)) = hv;
            }
    }
}

// ---------------- GEMM 2: agg + GIN mix ----------------
__global__ void __launch_bounds__(512) gemm_agg2(
    const float* __restrict__ adj,            // (B*H=32) x S x S f32
    const unsigned short* __restrict__ hhT,   // (B*I) x S bf16
    const unsigned short* __restrict__ hh,    // (B*S) x I bf16
    const float* __restrict__ eps, const float* __restrict__ alpha,
    unsigned short* __restrict__ hcomb)       // (B*S) x I bf16
{
    const int S = 2048, HD = 512, I = 8192;
    __shared__ unsigned short As[128 * 40];
    __shared__ unsigned short Bs[512 * 40];
    int bid = (int)blockIdx.x;
    int lb = (bid & 7) * 64 + (bid >> 3);
    int pair = lb >> 4;
    int mt = lb & 15;
    int b = pair >> 4, h = pair & 15;
    int tid = threadIdx.x;
    int lane = tid & 63;
    int wave = tid >> 6;
    int wm = wave >> 2, wn = wave & 3;
    f32x4 acc[4][8] = {};

    const float* Ab = adj + ((size_t)pair * S + (size_t)mt * 128) * S;
    const unsigned short* Bb = hhT + ((size_t)b * I + (size_t)h * HD) * (size_t)S;

    float4 pa0, pa1;
    int4 pb0, pb1, pb2, pb3;
    int a_row0 = tid >> 3, a_c = (tid & 7) << 2;
    int b_row0 = tid >> 2, b_ch = (tid & 3) << 3;

#define AGG_LOAD(K0)                                                              \
    do {                                                                          \
        pa0 = *(const float4*)(Ab + (size_t)a_row0 * S + (K0) + a_c);             \
        pa1 = *(const float4*)(Ab + (size_t)(a_row0 + 64) * S + (K0) + a_c);      \
        pb0 = *(const int4*)(Bb + (size_t)b_row0 * S + (K0) + b_ch);              \
        pb1 = *(const int4*)(Bb + (size_t)(b_row0 + 128) * S + (K0) + b_ch);      \
        pb2 = *(const int4*)(Bb + (size_t)(b_row0 + 256) * S + (K0) + b_ch);      \
        pb3 = *(const int4*)(Bb + (size_t)(b_row0 + 384) * S + (K0) + b_ch);      \
    } while (0)

#define AGG_WRITE()                                                               \
    do {                                                                          \
        ushort4 o0, o1;                                                           \
        o0.x = f2bf(pa0.x); o0.y = f2bf(pa0.y); o0.z = f2bf(pa0.z); o0.w = f2bf(pa0.w); \
        o1.x = f2bf(pa1.x); o1.y = f2bf(pa1.y); o1.z = f2bf(pa1.z); o1.w = f2bf(pa1.w); \
        *(ushort4*)((char*)As + a_row0 * 80 + a_c * 2) = o0;                      \
        *(ushort4*)((char*)As + (a_row0 + 64) * 80 + a_c * 2) = o1;               \
        *(int4*)((char*)Bs + b_row0 * 80 + b_ch * 2) = pb0;                       \
        *(int4*)((char*)Bs + (b_row0 + 128) * 80 + b_ch * 2) = pb1;               \
        *(int4*)((char*)Bs + (b_row0 + 256) * 80 + b_ch * 2) = pb2;               \
        *(int4*)((char*)Bs + (b_row0 + 384) * 80 + b_ch * 2) = pb3;               \
    } while (0)

    AGG_LOAD(0);
    AGG_WRITE();
    __syncthreads();

    int lrow = lane & 15;
    int koff2 = ((lane >> 4) << 3) * 2;
    const char* aptr = (const char*)As + (wm * 64 + lrow) * 80 + koff2;
    const char* bptr = (const char*)Bs + (wn * 128 + lrow) * 80 + koff2;

    for (int step = 0; step < 64; ++step) {
        bool more = (step + 1) < 64;
        if (more) AGG_LOAD((step + 1) * 32);
        bf16x8 af[4], bfv[8];
#pragma unroll
        for (int mi = 0; mi < 4; ++mi) af[mi] = *(const bf16x8*)(aptr + mi * 16 * 80);
#pragma unroll
        for (int ni = 0; ni < 8; ++ni) bfv[ni] = *(const bf16x8*)(bptr + ni * 16 * 80);
#pragma unroll
        for (int mi = 0; mi < 4; ++mi)
#pragma unroll
            for (int ni = 0; ni < 8; ++ni)
                acc[mi][ni] = __builtin_amdgcn_mfma_f32_16x16x32_bf16(af[mi], bfv[ni], acc[mi][ni], 0, 0, 0);
        __syncthreads();
        if (more) {
            AGG_WRITE();
            __syncthreads();
        }
    }
#undef AGG_LOAD
#undef AGG_WRITE

    float e1 = 1.f + eps[h];
    float a1 = alpha[h];
    int s_base = mt * 128 + wm * 64;
    int d_base = wn * 128;
#pragma unroll
    for (int mi = 0; mi < 4; ++mi)
#pragma unroll
        for (int ni = 0; ni < 8; ++ni) {
            int sb = s_base + mi * 16 + ((lane >> 4) << 2);
            int d = d_base + ni * 16 + (lane & 15);
#pragma unroll
            for (int r = 0; r < 4; ++r) {
                size_t off = ((size_t)(b * S + sb + r)) * I + (size_t)h * HD + d;
                float hv = bf2f(hh[off]);
                hcomb[off] = f2bf(e1 * hv + a1 * acc[mi][ni][r]);
            }
        }
}

// ---------------- GEMM 3: final projection ----------------
__global__ void __launch_bounds__(256) gemm_out(
    const unsigned short* __restrict__ hcomb, // 4096 x 8192
    const unsigned short* __restrict__ WdT,   // 2048 x 8192
    float* __restrict__ out)                  // 4096 x 2048
{
    const int K = 8192, N = 2048;
    __shared__ unsigned short As[128 * 64], Bs[128 * 64];
    int bid = blockIdx.x;
    int nt = bid & 15, mt = bid >> 4;
    int tid = threadIdx.x, wave = tid >> 6, lane = tid & 63;
    int wm = wave >> 1, wn = wave & 1;
    f32x4 acc[4][4] = {};
    const unsigned short* Ab = hcomb + (size_t)(mt * 128) * K;
    const unsigned short* Bb = WdT + (size_t)(nt * 128) * K;
    for (int k0 = 0; k0 < K; k0 += 64) {
        stage(As, Ab + k0, K, wave, lane);
        stage(Bs, Bb + k0, K, wave, lane);
        __syncthreads();
#pragma unroll
        for (int ki = 0; ki < 2; ++ki) {
            int kk = ki * 32 + ((lane >> 4) << 3);
            bf16x8 af[4], bfv[4];
#pragma unroll
            for (int mi = 0; mi < 4; ++mi) af[mi] = frag(As, wm * 64 + mi * 16 + (lane & 15), kk);
#pragma unroll
            for (int ni = 0; ni < 4; ++ni) bfv[ni] = frag(Bs, wn * 64 + ni * 16 + (lane & 15), kk);
#pragma unroll
            for (int mi = 0; mi < 4; ++mi)
#pragma unroll
                for (int ni = 0; ni < 4; ++ni)
                    acc[mi][ni] = __builtin_amdgcn_mfma_f32_16x16x32_bf16(af[mi], bfv[ni], acc[mi][ni], 0, 0, 0);
        }
        __syncthreads();
    }
    int m_off = mt * 128 + wm * 64, n_off = nt * 128 + wn * 64;
#pragma unroll
    for (int mi = 0; mi < 4; ++mi)
#pragma unroll
        for (int ni = 0; ni < 4; ++ni) {
            int mbase = m_off + mi * 16 + ((lane >> 4) << 2);
            int n = n_off + ni * 16 + (lane & 15);
#pragma unroll
            for (int r = 0; r < 4; ++r)
                out[(size_t)(mbase + r) * N + n] = acc[mi][ni][r];
        }
}

extern "C" void kernel_launch(void* const* d_in, const int* in_sizes, int n_in,
                              void* d_out, int out_size, void* d_ws, size_t ws_size,
                              hipStream_t stream) {
    const float* x     = (const float*)d_in[0];
    const float* adj   = (const float*)d_in[1];
    const float* Wg    = (const float*)d_in[2];
    const float* Wu    = (const float*)d_in[3];
    const float* Wd    = (const float*)d_in[4];
    const float* eps   = (const float*)d_in[5];
    const float* alpha = (const float*)d_in[6];
    float* out = (float*)d_out;

    unsigned short* ws    = (unsigned short*)d_ws;
    unsigned short* xb    = ws;                               // 4096*2048
    unsigned short* WgT   = xb + (size_t)4096 * 2048;         // 8192*2048
    unsigned short* WuT   = WgT + (size_t)8192 * 2048;        // 8192*2048
    unsigned short* WdT   = WuT + (size_t)8192 * 2048;        // 2048*8192
    unsigned short* hh    = WdT + (size_t)2048 * 8192;        // 4096*8192
    unsigned short* hhT   = hh + (size_t)4096 * 8192;         // 16384*2048
    unsigned short* hcomb = hhT + (size_t)16384 * 2048;       // 4096*8192
    unsigned short* gbuf  = hcomb;  // gate result overlays hcomb (dead before agg2 writes)

    conv_kernel<<<8192, 256, 0, stream>>>(x, xb);
    tconv_kernel<<<4096, 256, 0, stream>>>(Wg, WgT, 2048, 8192);
    tconv_kernel<<<4096, 256, 0, stream>>>(Wu, WuT, 2048, 8192);
    tconv_kernel<<<4096, 256, 0, stream>>>(Wd, WdT, 8192, 2048);
    gemm256<0><<<512, 512, 0, stream>>>(xb, WgT, nullptr, gbuf, nullptr, nullptr);
    gemm256<1><<<512, 512, 0, stream>>>(xb, WuT, gbuf, nullptr, hh, hhT);
    gemm_agg2<<<512, 512, 0, stream>>>(adj, hhT, hh, eps, alpha, hcomb);
    gemm_out<<<32 * 16, 256, 0, stream>>>(hcomb, WdT, out);
}

// Round 5
// 762.726 us; speedup vs baseline: 1.6268x; 1.0841x over previous
//
#include <hip/hip_runtime.h>
#include <hip/hip_bf16.h>

// B=2, S=2048, D=2048, H=16, I=8192, HD=512; M = B*S = 4096.

typedef __bf16 bf16x8 __attribute__((ext_vector_type(8)));
typedef float f32x4 __attribute__((ext_vector_type(4)));

__device__ __forceinline__ unsigned short f2bf(float f) {
    union { float f; unsigned int u; } x; x.f = f;
    unsigned int r = x.u + 0x7fffu + ((x.u >> 16) & 1u);  // RNE
    return (unsigned short)(r >> 16);
}
__device__ __forceinline__ float bf2f(unsigned short b) {
    union { unsigned int u; float f; } x; x.u = ((unsigned int)b) << 16;
    return x.f;
}

__device__ __forceinline__ void gload_lds16(const void* g, void* l) {
    __builtin_amdgcn_global_load_lds((const __attribute__((address_space(1))) void*)g,
                                     (__attribute__((address_space(3))) void*)l,
                                     16, 0, 0);
}

// ---------------- prep kernels ----------------

__global__ void conv_kernel(const float* __restrict__ in, unsigned short* __restrict__ out) {
    size_t i = ((size_t)blockIdx.x * 256 + threadIdx.x) * 4;
    float4 v = *(const float4*)(in + i);
    ushort4 o; o.x = f2bf(v.x); o.y = f2bf(v.y); o.z = f2bf(v.z); o.w = f2bf(v.w);
    *(ushort4*)(out + i) = o;
}

__global__ void tconv_kernel(const float* __restrict__ in, unsigned short* __restrict__ out,
                             int R, int C) {
    __shared__ float tile[64][65];
    int nbc = C >> 6;
    int bc = blockIdx.x % nbc, br = blockIdx.x / nbc;
    int r0 = br * 64, c0 = bc * 64;
    int t = threadIdx.x;
#pragma unroll
    for (int i = 0; i < 4; ++i) {
        int idx = i * 256 + t;
        int r = idx >> 4, c4 = (idx & 15) * 4;
        float4 v = *(const float4*)(in + (size_t)(r0 + r) * C + c0 + c4);
        tile[r][c4] = v.x; tile[r][c4 + 1] = v.y; tile[r][c4 + 2] = v.z; tile[r][c4 + 3] = v.w;
    }
    __syncthreads();
#pragma unroll
    for (int i = 0; i < 4; ++i) {
        int idx = i * 256 + t;
        int c = idx >> 4, r4 = (idx & 15) * 4;
        ushort4 o;
        o.x = f2bf(tile[r4][c]); o.y = f2bf(tile[r4 + 1][c]);
        o.z = f2bf(tile[r4 + 2][c]); o.w = f2bf(tile[r4 + 3][c]);
        *(ushort4*)(out + (size_t)(c0 + c) * R + r0 + r4) = o;
    }
}

// ---------------- 256x256 deep-pipelined GEMM for gate / up ----------------
template<int EPI>
__global__ void __launch_bounds__(512, 2) gemm256(
    const unsigned short* __restrict__ Ag,
    const unsigned short* __restrict__ Bg,
    const unsigned short* __restrict__ gbuf_c,
    unsigned short* __restrict__ gbuf,
    unsigned short* __restrict__ hh,
    unsigned short* __restrict__ hhT)
{
    const int K = 2048;
    __shared__ unsigned short LDS[4][16384];   // 128 KB total
    int bid = (int)blockIdx.x;
    int lb = (bid & 7) * 64 + (bid >> 3);      // bijective XCD chunk swizzle (512 = 8*64)
    int nt = lb & 31, mt = lb >> 5;
    int tid = threadIdx.x, lane = tid & 63, wave = tid >> 6;
    int wm = wave >> 2, wn = wave & 3;
    int l15 = lane & 15, l4 = lane >> 4;

    f32x4 acc[8][4] = {};

    int jl = (lane & 7) ^ (lane >> 3);
    int prow0 = wave * 16 + (lane >> 3);
    int row0 = prow0 + ((jl & 4) << 5);
    int cc = (jl & 3) << 3;
    const unsigned short* srcA0 = Ag + (size_t)(mt * 256 + row0) * K + cc;
    const unsigned short* srcA1 = srcA0 + (size_t)8 * K;
    const unsigned short* srcB0 = Bg + (size_t)(nt * 256 + row0) * K + cc;
    const unsigned short* srcB1 = srcB0 + (size_t)8 * K;

    int cA = l15 * 128 + (((l4 + wm * 4) ^ (l15 & 7)) << 4);
    int cB = ((wn & 1) * 64 + l15) * 128 + (((l4 + ((wn >> 1) << 2)) ^ (l15 & 7)) << 4);

#define STAGE_A(t_) do { char* d_ = (char*)&LDS[(t_) & 3][0] + wave * 2048;              \
        gload_lds16((const void*)(srcA0 + (size_t)(t_) * 32), (void*)d_);                \
        gload_lds16((const void*)(srcA1 + (size_t)(t_) * 32), (void*)(d_ + 1024)); } while (0)
#define STAGE_B(t_) do { char* d_ = (char*)&LDS[(t_) & 3][8192] + wave * 2048;           \
        gload_lds16((const void*)(srcB0 + (size_t)(t_) * 32), (void*)d_);                \
        gload_lds16((const void*)(srcB1 + (size_t)(t_) * 32), (void*)(d_ + 1024)); } while (0)

    STAGE_A(0); STAGE_B(0);
    STAGE_A(1); STAGE_B(1);

    for (int t = 0; t < 64; ++t) {
        // tail-safe counted wait: once nothing more is issued, the no-op vmcnt(4)
        // would race the final tile's in-flight loads -> drain fully instead.
        if (t + 2 < 64) asm volatile("s_waitcnt vmcnt(4)" ::: "memory");
        else            asm volatile("s_waitcnt vmcnt(0)" ::: "memory");
        __builtin_amdgcn_s_barrier();
        const char* Abase = (const char*)&LDS[t & 3][0];
        const char* Bbase = Abase + 16384;
        bool more = (t + 2) < 64;
        if (more) STAGE_A(t + 2);
        bf16x8 bf[4], af[4];
#pragma unroll
        for (int ni = 0; ni < 4; ++ni) bf[ni] = *(const bf16x8*)(Bbase + cB + ni * 2048);
#pragma unroll
        for (int mi = 0; mi < 4; ++mi) af[mi] = *(const bf16x8*)(Abase + cA + mi * 2048);
        __builtin_amdgcn_s_setprio(1);
#pragma unroll
        for (int mi = 0; mi < 4; ++mi)
#pragma unroll
            for (int ni = 0; ni < 4; ++ni)
                acc[mi][ni] = __builtin_amdgcn_mfma_f32_16x16x32_bf16(af[mi], bf[ni], acc[mi][ni], 0, 0, 0);
        __builtin_amdgcn_s_setprio(0);
        if (more) STAGE_B(t + 2);
#pragma unroll
        for (int mi = 0; mi < 4; ++mi) af[mi] = *(const bf16x8*)(Abase + cA + 8192 + mi * 2048);
        __builtin_amdgcn_s_setprio(1);
#pragma unroll
        for (int mi = 0; mi < 4; ++mi)
#pragma unroll
            for (int ni = 0; ni < 4; ++ni)
                acc[4 + mi][ni] = __builtin_amdgcn_mfma_f32_16x16x32_bf16(af[mi], bf[ni], acc[4 + mi][ni], 0, 0, 0);
        __builtin_amdgcn_s_setprio(0);
    }
#undef STAGE_A
#undef STAGE_B

    if (EPI == 0) {
        ushort4* g4 = (ushort4*)gbuf;
        size_t base = ((size_t)lb * 32) * 512 + tid;
#pragma unroll
        for (int a = 0; a < 8; ++a)
#pragma unroll
            for (int ni = 0; ni < 4; ++ni) {
                f32x4 v = acc[a][ni];
                ushort4 o;
                o.x = f2bf(v[0]); o.y = f2bf(v[1]); o.z = f2bf(v[2]); o.w = f2bf(v[3]);
                g4[base + (size_t)(a * 4 + ni) * 512] = o;
            }
    } else {
        const ushort4* g4 = (const ushort4*)gbuf_c;
        size_t base = ((size_t)lb * 32) * 512 + tid;
        int rowb = mt * 256 + wm * 128 + l4 * 4;
        int colb = nt * 256 + wn * 64 + l15;
        int b = mt >> 3;
#pragma unroll
        for (int a = 0; a < 8; ++a)
#pragma unroll
            for (int ni = 0; ni < 4; ++ni) {
                ushort4 gq = g4[base + (size_t)(a * 4 + ni) * 512];
                int row = rowb + a * 16;
                int n = colb + ni * 16;
                ushort4 hv;
#pragma unroll
                for (int r = 0; r < 4; ++r) {
                    float gv = bf2f(((const unsigned short*)&gq)[r]);
                    float u = acc[a][ni][r];
                    float h = gv / (1.f + __expf(-gv)) * u;
                    unsigned short hb = f2bf(h);
                    ((unsigned short*)&hv)[r] = hb;
                    hh[(size_t)(row + r) * 8192 + n] = hb;
                }
                *(ushort4*)(hhT + ((size_t)b * 8192 + n) * 2048 + (row & 2047)) = hv;
            }
    }
}

// ---------------- GEMM 2 v3: agg + GIN mix, double-buffered 1-barrier ----------------
__global__ void __launch_bounds__(512, 2) gemm_agg3(
    const float* __restrict__ adj,            // (B*H=32) x S x S f32
    const unsigned short* __restrict__ hhT,   // (B*I) x S bf16
    const unsigned short* __restrict__ hh,    // (B*S) x I bf16
    const float* __restrict__ eps, const float* __restrict__ alpha,
    unsigned short* __restrict__ hcomb)       // (B*S) x I bf16
{
    const int S = 2048, HD = 512, I = 8192;
    __shared__ unsigned short As[2][128 * 40];   // 2 x 10 KB
    __shared__ unsigned short Bs[2][512 * 40];   // 2 x 40 KB
    int bid = (int)blockIdx.x;
    int lb = (bid & 7) * 64 + (bid >> 3);
    int pair = lb >> 4;
    int mt = lb & 15;
    int b = pair >> 4, h = pair & 15;
    int tid = threadIdx.x;
    int lane = tid & 63;
    int wave = tid >> 6;
    int wm = wave >> 2, wn = wave & 3;
    f32x4 acc[4][8] = {};

    const float* Ab = adj + ((size_t)pair * S + (size_t)mt * 128) * S;
    const unsigned short* Bb = hhT + ((size_t)b * I + (size_t)h * HD) * (size_t)S;

    int a_row0 = tid >> 3, a_c = (tid & 7) << 2;
    int b_row0 = tid >> 2, b_ch = (tid & 3) << 3;

    // two named prefetch register sets (static indexing, rule #20)
    float4 pa0_0, pa1_0, pa0_1, pa1_1;
    int4 pb0_0, pb1_0, pb2_0, pb3_0, pb0_1, pb1_1, pb2_1, pb3_1;

#define AGG_LOAD(SET, K0)                                                               \
    do {                                                                                \
        pa0_##SET = *(const float4*)(Ab + (size_t)a_row0 * S + (K0) + a_c);             \
        pa1_##SET = *(const float4*)(Ab + (size_t)(a_row0 + 64) * S + (K0) + a_c);      \
        pb0_##SET = *(const int4*)(Bb + (size_t)b_row0 * S + (K0) + b_ch);              \
        pb1_##SET = *(const int4*)(Bb + (size_t)(b_row0 + 128) * S + (K0) + b_ch);      \
        pb2_##SET = *(const int4*)(Bb + (size_t)(b_row0 + 256) * S + (K0) + b_ch);      \
        pb3_##SET = *(const int4*)(Bb + (size_t)(b_row0 + 384) * S + (K0) + b_ch);      \
    } while (0)

#define AGG_WRITE(SET, BUF)                                                             \
    do {                                                                                \
        ushort4 o0, o1;                                                                 \
        o0.x = f2bf(pa0_##SET.x); o0.y = f2bf(pa0_##SET.y);                             \
        o0.z = f2bf(pa0_##SET.z); o0.w = f2bf(pa0_##SET.w);                             \
        o1.x = f2bf(pa1_##SET.x); o1.y = f2bf(pa1_##SET.y);                             \
        o1.z = f2bf(pa1_##SET.z); o1.w = f2bf(pa1_##SET.w);                             \
        *(ushort4*)((char*)As[BUF] + a_row0 * 80 + a_c * 2) = o0;                       \
        *(ushort4*)((char*)As[BUF] + (a_row0 + 64) * 80 + a_c * 2) = o1;                \
        *(int4*)((char*)Bs[BUF] + b_row0 * 80 + b_ch * 2) = pb0_##SET;                  \
        *(int4*)((char*)Bs[BUF] + (b_row0 + 128) * 80 + b_ch * 2) = pb1_##SET;          \
        *(int4*)((char*)Bs[BUF] + (b_row0 + 256) * 80 + b_ch * 2) = pb2_##SET;          \
        *(int4*)((char*)Bs[BUF] + (b_row0 + 384) * 80 + b_ch * 2) = pb3_##SET;          \
    } while (0)

    int lrow = lane & 15;
    int koff2 = ((lane >> 4) << 3) * 2;
    const char* aptr0 = (const char*)As[0] + (wm * 64 + lrow) * 80 + koff2;
    const char* bptr0 = (const char*)Bs[0] + (wn * 128 + lrow) * 80 + koff2;
    const char* aptr1 = (const char*)As[1] + (wm * 64 + lrow) * 80 + koff2;
    const char* bptr1 = (const char*)Bs[1] + (wn * 128 + lrow) * 80 + koff2;

#define AGG_COMPUTE(APTR, BPTR)                                                         \
    do {                                                                                \
        bf16x8 af[4], bfv[8];                                                           \
        _Pragma("unroll")                                                               \
        for (int mi = 0; mi < 4; ++mi) af[mi] = *(const bf16x8*)((APTR) + mi * 16 * 80);\
        _Pragma("unroll")                                                               \
        for (int ni = 0; ni < 8; ++ni) bfv[ni] = *(const bf16x8*)((BPTR) + ni * 16 * 80);\
        __builtin_amdgcn_s_setprio(1);                                                  \
        _Pragma("unroll")                                                               \
        for (int mi = 0; mi < 4; ++mi)                                                  \
            _Pragma("unroll")                                                           \
            for (int ni = 0; ni < 8; ++ni)                                              \
                acc[mi][ni] = __builtin_amdgcn_mfma_f32_16x16x32_bf16(af[mi], bfv[ni],  \
                                                                      acc[mi][ni], 0, 0, 0); \
        __builtin_amdgcn_s_setprio(0);                                                  \
    } while (0)

    // prologue: step0 -> buf0, issue step1 into set1
    AGG_LOAD(0, 0);
    AGG_WRITE(0, 0);
    AGG_LOAD(1, 32);
    asm volatile("s_waitcnt lgkmcnt(0)" ::: "memory");
    __builtin_amdgcn_s_barrier();

    for (int s = 0; s < 64; s += 2) {
        // even substep: compute buf0 (step s); set1 holds s+1 -> buf1
        if (s + 2 < 64) AGG_LOAD(0, (s + 2) * 32);
        AGG_COMPUTE(aptr0, bptr0);
        AGG_WRITE(1, 1);
        asm volatile("s_waitcnt lgkmcnt(0)" ::: "memory");
        __builtin_amdgcn_s_barrier();
        // odd substep: compute buf1 (step s+1); set0 holds s+2 -> buf0
        if (s + 3 < 64) AGG_LOAD(1, (s + 3) * 32);
        AGG_COMPUTE(aptr1, bptr1);
        if (s + 2 < 64) {
            AGG_WRITE(0, 0);
            asm volatile("s_waitcnt lgkmcnt(0)" ::: "memory");
            __builtin_amdgcn_s_barrier();
        }
    }
#undef AGG_LOAD
#undef AGG_WRITE
#undef AGG_COMPUTE

    float e1 = 1.f + eps[h];
    float a1 = alpha[h];
    int s_base = mt * 128 + wm * 64;
    int d_base = wn * 128;
#pragma unroll
    for (int mi = 0; mi < 4; ++mi)
#pragma unroll
        for (int ni = 0; ni < 8; ++ni) {
            int sb = s_base + mi * 16 + ((lane >> 4) << 2);
            int d = d_base + ni * 16 + (lane & 15);
#pragma unroll
            for (int r = 0; r < 4; ++r) {
                size_t off = ((size_t)(b * S + sb + r)) * I + (size_t)h * HD + d;
                float hv = bf2f(hh[off]);
                hcomb[off] = f2bf(e1 * hv + a1 * acc[mi][ni][r]);
            }
        }
}

// ---------------- GEMM 3 v2: final projection, deep-pipelined 256x128 ----------------
__global__ void __launch_bounds__(512, 2) gemm_out2(
    const unsigned short* __restrict__ hcomb, // 4096 x 8192
    const unsigned short* __restrict__ WdT,   // 2048 x 8192
    float* __restrict__ out)                  // 4096 x 2048
{
    const int K = 8192;
    __shared__ unsigned short LDS[4][12288];  // per buf: A 8192 + B 4096 ushorts = 24 KB
    int bid = (int)blockIdx.x;
    int lb = (bid & 7) * 32 + (bid >> 3);     // bijective: 256 = 8 * 32
    int mt = lb >> 4, nt = lb & 15;           // mt-major chunks: A-panel L2 reuse per XCD
    int tid = threadIdx.x, lane = tid & 63, wave = tid >> 6;
    int wm = wave >> 1, wn = wave & 1;        // 4M x 2N waves, wave tile 64x64
    int l15 = lane & 15, l4 = lane >> 4;
    f32x4 acc[4][4] = {};

    int jl = (lane & 7) ^ (lane >> 3);
    int prowA = wave * 16 + (lane >> 3);
    int rowA0 = prowA + ((jl & 4) << 5);
    int ccA = (jl & 3) << 3;
    const unsigned short* srcA0 = hcomb + (size_t)(mt * 256 + rowA0) * K + ccA;
    const unsigned short* srcA1 = srcA0 + (size_t)8 * K;
    int prowB = tid >> 3;
    int jbl = (tid & 7) ^ (prowB & 7);
    int rowB0 = prowB + ((jbl & 4) << 4);
    int ccB = (jbl & 3) << 3;
    const unsigned short* srcB0 = WdT + (size_t)(nt * 128 + rowB0) * K + ccB;

    int cA0 = ((wm & 1) * 64 + l15) * 128 + (((((wm >> 1) << 2) + l4) ^ (l15 & 7)) << 4);
    int cB0 = l15 * 128 + ((((wn << 2) + l4) ^ (l15 & 7)) << 4);

#define OSTAGE(t_) do {                                                                  \
        char* dA = (char*)&LDS[(t_) & 3][0] + wave * 2048;                               \
        gload_lds16((const void*)(srcA0 + (size_t)(t_) * 32), (void*)dA);                \
        gload_lds16((const void*)(srcA1 + (size_t)(t_) * 32), (void*)(dA + 1024));       \
        char* dB = (char*)&LDS[(t_) & 3][8192] + wave * 1024;                            \
        gload_lds16((const void*)(srcB0 + (size_t)(t_) * 32), (void*)dB);                \
    } while (0)

    OSTAGE(0); OSTAGE(1);

    for (int t = 0; t < 256; ++t) {
        // tail-safe counted wait (ROUND-4 BUG FIX): at t=255 only tile 255's 3 loads
        // are outstanding, so vmcnt(3) was a no-op and the body read un-landed LDS.
        if (t + 2 < 256) asm volatile("s_waitcnt vmcnt(3)" ::: "memory");
        else             asm volatile("s_waitcnt vmcnt(0)" ::: "memory");
        __builtin_amdgcn_s_barrier();
        const char* Abase = (const char*)&LDS[t & 3][0];
        const char* Bbase = Abase + 16384;
        bool more = (t + 2) < 256;
        bf16x8 af[4], bf[4];
#pragma unroll
        for (int ni = 0; ni < 4; ++ni) bf[ni] = *(const bf16x8*)(Bbase + cB0 + ni * 2048);
        if (more) OSTAGE(t + 2);
#pragma unroll
        for (int mi = 0; mi < 4; ++mi) af[mi] = *(const bf16x8*)(Abase + cA0 + mi * 2048);
        __builtin_amdgcn_s_setprio(1);
#pragma unroll
        for (int mi = 0; mi < 4; ++mi)
#pragma unroll
            for (int ni = 0; ni < 4; ++ni)
                acc[mi][ni] = __builtin_amdgcn_mfma_f32_16x16x32_bf16(af[mi], bf[ni], acc[mi][ni], 0, 0, 0);
        __builtin_amdgcn_s_setprio(0);
    }
#undef OSTAGE

    int m_off = mt * 256 + wm * 64, n_off = nt * 128 + wn * 64;
#pragma unroll
    for (int mi = 0; mi < 4; ++mi)
#pragma unroll
        for (int ni = 0; ni < 4; ++ni) {
            int mbase = m_off + mi * 16 + l4 * 4;
            int n = n_off + ni * 16 + l15;
#pragma unroll
            for (int r = 0; r < 4; ++r)
                out[(size_t)(mbase + r) * 2048 + n] = acc[mi][ni][r];
        }
}

extern "C" void kernel_launch(void* const* d_in, const int* in_sizes, int n_in,
                              void* d_out, int out_size, void* d_ws, size_t ws_size,
                              hipStream_t stream) {
    const float* x     = (const float*)d_in[0];
    const float* adj   = (const float*)d_in[1];
    const float* Wg    = (const float*)d_in[2];
    const float* Wu    = (const float*)d_in[3];
    const float* Wd    = (const float*)d_in[4];
    const float* eps   = (const float*)d_in[5];
    const float* alpha = (const float*)d_in[6];
    float* out = (float*)d_out;

    unsigned short* ws    = (unsigned short*)d_ws;
    unsigned short* xb    = ws;                               // 4096*2048
    unsigned short* WgT   = xb + (size_t)4096 * 2048;         // 8192*2048
    unsigned short* WuT   = WgT + (size_t)8192 * 2048;        // 8192*2048
    unsigned short* WdT   = WuT + (size_t)8192 * 2048;        // 2048*8192
    unsigned short* hh    = WdT + (size_t)2048 * 8192;        // 4096*8192
    unsigned short* hhT   = hh + (size_t)4096 * 8192;         // 16384*2048
    unsigned short* hcomb = hhT + (size_t)16384 * 2048;       // 4096*8192
    unsigned short* gbuf  = hcomb;  // gate result overlays hcomb (dead before agg3 writes)

    conv_kernel<<<8192, 256, 0, stream>>>(x, xb);
    tconv_kernel<<<4096, 256, 0, stream>>>(Wg, WgT, 2048, 8192);
    tconv_kernel<<<4096, 256, 0, stream>>>(Wu, WuT, 2048, 8192);
    tconv_kernel<<<4096, 256, 0, stream>>>(Wd, WdT, 8192, 2048);
    gemm256<0><<<512, 512, 0, stream>>>(xb, WgT, nullptr, gbuf, nullptr, nullptr);
    gemm256<1><<<512, 512, 0, stream>>>(xb, WuT, gbuf, nullptr, hh, hhT);
    gemm_agg3<<<512, 512, 0, stream>>>(adj, hhT, hh, eps, alpha, hcomb);
    gemm_out2<<<256, 512, 0, stream>>>(hcomb, WdT, out);
}

// Round 6
// 719.052 us; speedup vs baseline: 1.7256x; 1.0607x over previous
//
#include <hip/hip_runtime.h>
#include <hip/hip_bf16.h>

// B=2, S=2048, D=2048, H=16, I=8192, HD=512; M = B*S = 4096.

typedef __bf16 bf16x8 __attribute__((ext_vector_type(8)));
typedef float f32x4 __attribute__((ext_vector_type(4)));

__device__ __forceinline__ unsigned short f2bf(float f) {
    union { float f; unsigned int u; } x; x.f = f;
    unsigned int r = x.u + 0x7fffu + ((x.u >> 16) & 1u);  // RNE
    return (unsigned short)(r >> 16);
}
__device__ __forceinline__ float bf2f(unsigned short b) {
    union { unsigned int u; float f; } x; x.u = ((unsigned int)b) << 16;
    return x.f;
}

__device__ __forceinline__ void gload_lds16(const void* g, void* l) {
    __builtin_amdgcn_global_load_lds((const __attribute__((address_space(1))) void*)g,
                                     (__attribute__((address_space(3))) void*)l,
                                     16, 0, 0);
}

// ---------------- prep kernels ----------------

__global__ void conv_kernel(const float* __restrict__ in, unsigned short* __restrict__ out) {
    size_t i = ((size_t)blockIdx.x * 256 + threadIdx.x) * 4;
    float4 v = *(const float4*)(in + i);
    ushort4 o; o.x = f2bf(v.x); o.y = f2bf(v.y); o.z = f2bf(v.z); o.w = f2bf(v.w);
    *(ushort4*)(out + i) = o;
}

__global__ void tconv_kernel(const float* __restrict__ in, unsigned short* __restrict__ out,
                             int R, int C) {
    __shared__ float tile[64][65];
    int nbc = C >> 6;
    int bc = blockIdx.x % nbc, br = blockIdx.x / nbc;
    int r0 = br * 64, c0 = bc * 64;
    int t = threadIdx.x;
#pragma unroll
    for (int i = 0; i < 4; ++i) {
        int idx = i * 256 + t;
        int r = idx >> 4, c4 = (idx & 15) * 4;
        float4 v = *(const float4*)(in + (size_t)(r0 + r) * C + c0 + c4);
        tile[r][c4] = v.x; tile[r][c4 + 1] = v.y; tile[r][c4 + 2] = v.z; tile[r][c4 + 3] = v.w;
    }
    __syncthreads();
#pragma unroll
    for (int i = 0; i < 4; ++i) {
        int idx = i * 256 + t;
        int c = idx >> 4, r4 = (idx & 15) * 4;
        ushort4 o;
        o.x = f2bf(tile[r4][c]); o.y = f2bf(tile[r4 + 1][c]);
        o.z = f2bf(tile[r4 + 2][c]); o.w = f2bf(tile[r4 + 3][c]);
        *(ushort4*)(out + (size_t)(c0 + c) * R + r0 + r4) = o;
    }
}

// ---------------- 256x256 deep-pipelined GEMM for gate / up ----------------
template<int EPI>
__global__ void __launch_bounds__(512, 2) gemm256(
    const unsigned short* __restrict__ Ag,
    const unsigned short* __restrict__ Bg,
    const unsigned short* __restrict__ gbuf_c,
    unsigned short* __restrict__ gbuf,
    unsigned short* __restrict__ hhT)
{
    const int K = 2048;
    __shared__ unsigned short LDS[4][16384];   // 128 KB total
    int bid = (int)blockIdx.x;
    int lb = (bid & 7) * 64 + (bid >> 3);      // bijective XCD chunk swizzle (512 = 8*64)
    int nt = lb & 31, mt = lb >> 5;
    int tid = threadIdx.x, lane = tid & 63, wave = tid >> 6;
    int wm = wave >> 2, wn = wave & 3;
    int l15 = lane & 15, l4 = lane >> 4;

    f32x4 acc[8][4] = {};

    int jl = (lane & 7) ^ (lane >> 3);
    int prow0 = wave * 16 + (lane >> 3);
    int row0 = prow0 + ((jl & 4) << 5);
    int cc = (jl & 3) << 3;
    const unsigned short* srcA0 = Ag + (size_t)(mt * 256 + row0) * K + cc;
    const unsigned short* srcA1 = srcA0 + (size_t)8 * K;
    const unsigned short* srcB0 = Bg + (size_t)(nt * 256 + row0) * K + cc;
    const unsigned short* srcB1 = srcB0 + (size_t)8 * K;

    int cA = l15 * 128 + (((l4 + wm * 4) ^ (l15 & 7)) << 4);
    int cB = ((wn & 1) * 64 + l15) * 128 + (((l4 + ((wn >> 1) << 2)) ^ (l15 & 7)) << 4);

#define STAGE_A(t_) do { char* d_ = (char*)&LDS[(t_) & 3][0] + wave * 2048;              \
        gload_lds16((const void*)(srcA0 + (size_t)(t_) * 32), (void*)d_);                \
        gload_lds16((const void*)(srcA1 + (size_t)(t_) * 32), (void*)(d_ + 1024)); } while (0)
#define STAGE_B(t_) do { char* d_ = (char*)&LDS[(t_) & 3][8192] + wave * 2048;           \
        gload_lds16((const void*)(srcB0 + (size_t)(t_) * 32), (void*)d_);                \
        gload_lds16((const void*)(srcB1 + (size_t)(t_) * 32), (void*)(d_ + 1024)); } while (0)

    STAGE_A(0); STAGE_B(0);
    STAGE_A(1); STAGE_B(1);

    for (int t = 0; t < 64; ++t) {
        // tail-safe counted wait
        if (t + 2 < 64) asm volatile("s_waitcnt vmcnt(4)" ::: "memory");
        else            asm volatile("s_waitcnt vmcnt(0)" ::: "memory");
        __builtin_amdgcn_s_barrier();
        const char* Abase = (const char*)&LDS[t & 3][0];
        const char* Bbase = Abase + 16384;
        bool more = (t + 2) < 64;
        if (more) STAGE_A(t + 2);
        bf16x8 bf[4], af[4];
#pragma unroll
        for (int ni = 0; ni < 4; ++ni) bf[ni] = *(const bf16x8*)(Bbase + cB + ni * 2048);
#pragma unroll
        for (int mi = 0; mi < 4; ++mi) af[mi] = *(const bf16x8*)(Abase + cA + mi * 2048);
        __builtin_amdgcn_s_setprio(1);
#pragma unroll
        for (int mi = 0; mi < 4; ++mi)
#pragma unroll
            for (int ni = 0; ni < 4; ++ni)
                acc[mi][ni] = __builtin_amdgcn_mfma_f32_16x16x32_bf16(af[mi], bf[ni], acc[mi][ni], 0, 0, 0);
        __builtin_amdgcn_s_setprio(0);
        if (more) STAGE_B(t + 2);
#pragma unroll
        for (int mi = 0; mi < 4; ++mi) af[mi] = *(const bf16x8*)(Abase + cA + 8192 + mi * 2048);
        __builtin_amdgcn_s_setprio(1);
#pragma unroll
        for (int mi = 0; mi < 4; ++mi)
#pragma unroll
            for (int ni = 0; ni < 4; ++ni)
                acc[4 + mi][ni] = __builtin_amdgcn_mfma_f32_16x16x32_bf16(af[mi], bf[ni], acc[4 + mi][ni], 0, 0, 0);
        __builtin_amdgcn_s_setprio(0);
    }
#undef STAGE_A
#undef STAGE_B

    if (EPI == 0) {
        ushort4* g4 = (ushort4*)gbuf;
        size_t base = ((size_t)lb * 32) * 512 + tid;
#pragma unroll
        for (int a = 0; a < 8; ++a)
#pragma unroll
            for (int ni = 0; ni < 4; ++ni) {
                f32x4 v = acc[a][ni];
                ushort4 o;
                o.x = f2bf(v[0]); o.y = f2bf(v[1]); o.z = f2bf(v[2]); o.w = f2bf(v[3]);
                g4[base + (size_t)(a * 4 + ni) * 512] = o;
            }
    } else {
        const ushort4* g4 = (const ushort4*)gbuf_c;
        size_t base = ((size_t)lb * 32) * 512 + tid;
        int rowb = mt * 256 + wm * 128 + l4 * 4;
        int colb = nt * 256 + wn * 64 + l15;
        int b = mt >> 3;
#pragma unroll
        for (int a = 0; a < 8; ++a)
#pragma unroll
            for (int ni = 0; ni < 4; ++ni) {
                ushort4 gq = g4[base + (size_t)(a * 4 + ni) * 512];
                int row = rowb + a * 16;
                int n = colb + ni * 16;
                ushort4 hv;
#pragma unroll
                for (int r = 0; r < 4; ++r) {
                    float gv = bf2f(((const unsigned short*)&gq)[r]);
                    float u = acc[a][ni][r];
                    float h = gv / (1.f + __expf(-gv)) * u;
                    ((unsigned short*)&hv)[r] = f2bf(h);
                }
                // only hhT is written (hh eliminated; e*h folded into agg's diagonal)
                *(ushort4*)(hhT + ((size_t)b * 8192 + n) * 2048 + (row & 2047)) = hv;
            }
    }
}

// ---------------- GEMM 2 v4: agg + GIN mix, diag-folded ----------------
// h_gin = e1*h + a1*(adj@h) = a1 * ((adj + (e1/a1) I) @ h)  -> fold e1/a1 into the
// diagonal during f32->bf16 A-staging; epilogue is just a1*acc. No hh read.
__global__ void __launch_bounds__(512, 2) gemm_agg3(
    const float* __restrict__ adj,            // (B*H=32) x S x S f32
    const unsigned short* __restrict__ hhT,   // (B*I) x S bf16
    const float* __restrict__ eps, const float* __restrict__ alpha,
    unsigned short* __restrict__ hcomb)       // (B*S) x I bf16
{
    const int S = 2048, HD = 512, I = 8192;
    __shared__ unsigned short As[2][128 * 40];   // 2 x 10 KB
    __shared__ unsigned short Bs[2][512 * 40];   // 2 x 40 KB
    int bid = (int)blockIdx.x;
    int lb = (bid & 7) * 64 + (bid >> 3);
    int pair = lb >> 4;
    int mt = lb & 15;
    int b = pair >> 4, h = pair & 15;
    int tid = threadIdx.x;
    int lane = tid & 63;
    int wave = tid >> 6;
    int wm = wave >> 2, wn = wave & 3;
    f32x4 acc[4][8] = {};

    float e1 = 1.f + eps[h];
    float a1 = alpha[h];
    bool a1z = (a1 == 0.f);
    float dfac = a1z ? 0.f : (e1 / a1);

    const float* Ab = adj + ((size_t)pair * S + (size_t)mt * 128) * S;
    const unsigned short* Bb = hhT + ((size_t)b * I + (size_t)h * HD) * (size_t)S;

    int a_row0 = tid >> 3, a_c = (tid & 7) << 2;
    int grow0 = mt * 128 + a_row0;           // global s-row of pa0 (pa1 = +64)
    int b_row0 = tid >> 2, b_ch = (tid & 3) << 3;

    float4 pa0_0, pa1_0, pa0_1, pa1_1;
    int4 pb0_0, pb1_0, pb2_0, pb3_0, pb0_1, pb1_1, pb2_1, pb3_1;

#define AGG_LOAD(SET, K0)                                                               \
    do {                                                                                \
        pa0_##SET = *(const float4*)(Ab + (size_t)a_row0 * S + (K0) + a_c);             \
        pa1_##SET = *(const float4*)(Ab + (size_t)(a_row0 + 64) * S + (K0) + a_c);      \
        pb0_##SET = *(const int4*)(Bb + (size_t)b_row0 * S + (K0) + b_ch);              \
        pb1_##SET = *(const int4*)(Bb + (size_t)(b_row0 + 128) * S + (K0) + b_ch);      \
        pb2_##SET = *(const int4*)(Bb + (size_t)(b_row0 + 256) * S + (K0) + b_ch);      \
        pb3_##SET = *(const int4*)(Bb + (size_t)(b_row0 + 384) * S + (K0) + b_ch);      \
    } while (0)

// fold (e1/a1) into the diagonal element if it falls in this thread's 4 k-slots
#define AGG_WRITE(SET, BUF, K0)                                                         \
    do {                                                                                \
        int j0 = grow0 - (K0) - a_c;                                                    \
        pa0_##SET.x += (j0 == 0) ? dfac : 0.f;                                          \
        pa0_##SET.y += (j0 == 1) ? dfac : 0.f;                                          \
        pa0_##SET.z += (j0 == 2) ? dfac : 0.f;                                          \
        pa0_##SET.w += (j0 == 3) ? dfac : 0.f;                                          \
        int j1 = j0 + 64;                                                               \
        pa1_##SET.x += (j1 == 0) ? dfac : 0.f;                                          \
        pa1_##SET.y += (j1 == 1) ? dfac : 0.f;                                          \
        pa1_##SET.z += (j1 == 2) ? dfac : 0.f;                                          \
        pa1_##SET.w += (j1 == 3) ? dfac : 0.f;                                          \
        ushort4 o0, o1;                                                                 \
        o0.x = f2bf(pa0_##SET.x); o0.y = f2bf(pa0_##SET.y);                             \
        o0.z = f2bf(pa0_##SET.z); o0.w = f2bf(pa0_##SET.w);                             \
        o1.x = f2bf(pa1_##SET.x); o1.y = f2bf(pa1_##SET.y);                             \
        o1.z = f2bf(pa1_##SET.z); o1.w = f2bf(pa1_##SET.w);                             \
        *(ushort4*)((char*)As[BUF] + a_row0 * 80 + a_c * 2) = o0;                       \
        *(ushort4*)((char*)As[BUF] + (a_row0 + 64) * 80 + a_c * 2) = o1;                \
        *(int4*)((char*)Bs[BUF] + b_row0 * 80 + b_ch * 2) = pb0_##SET;                  \
        *(int4*)((char*)Bs[BUF] + (b_row0 + 128) * 80 + b_ch * 2) = pb1_##SET;          \
        *(int4*)((char*)Bs[BUF] + (b_row0 + 256) * 80 + b_ch * 2) = pb2_##SET;          \
        *(int4*)((char*)Bs[BUF] + (b_row0 + 384) * 80 + b_ch * 2) = pb3_##SET;          \
    } while (0)

    int lrow = lane & 15;
    int koff2 = ((lane >> 4) << 3) * 2;
    const char* aptr0 = (const char*)As[0] + (wm * 64 + lrow) * 80 + koff2;
    const char* bptr0 = (const char*)Bs[0] + (wn * 128 + lrow) * 80 + koff2;
    const char* aptr1 = (const char*)As[1] + (wm * 64 + lrow) * 80 + koff2;
    const char* bptr1 = (const char*)Bs[1] + (wn * 128 + lrow) * 80 + koff2;

#define AGG_COMPUTE(APTR, BPTR)                                                         \
    do {                                                                                \
        bf16x8 af[4], bfv[8];                                                           \
        _Pragma("unroll")                                                               \
        for (int mi = 0; mi < 4; ++mi) af[mi] = *(const bf16x8*)((APTR) + mi * 16 * 80);\
        _Pragma("unroll")                                                               \
        for (int ni = 0; ni < 8; ++ni) bfv[ni] = *(const bf16x8*)((BPTR) + ni * 16 * 80);\
        __builtin_amdgcn_s_setprio(1);                                                  \
        _Pragma("unroll")                                                               \
        for (int mi = 0; mi < 4; ++mi)                                                  \
            _Pragma("unroll")                                                           \
            for (int ni = 0; ni < 8; ++ni)                                              \
                acc[mi][ni] = __builtin_amdgcn_mfma_f32_16x16x32_bf16(af[mi], bfv[ni],  \
                                                                      acc[mi][ni], 0, 0, 0); \
        __builtin_amdgcn_s_setprio(0);                                                  \
    } while (0)

    AGG_LOAD(0, 0);
    AGG_WRITE(0, 0, 0);
    AGG_LOAD(1, 32);
    asm volatile("s_waitcnt lgkmcnt(0)" ::: "memory");
    __builtin_amdgcn_s_barrier();

    for (int s = 0; s < 64; s += 2) {
        if (s + 2 < 64) AGG_LOAD(0, (s + 2) * 32);
        AGG_COMPUTE(aptr0, bptr0);
        AGG_WRITE(1, 1, (s + 1) * 32);
        asm volatile("s_waitcnt lgkmcnt(0)" ::: "memory");
        __builtin_amdgcn_s_barrier();
        if (s + 3 < 64) AGG_LOAD(1, (s + 3) * 32);
        AGG_COMPUTE(aptr1, bptr1);
        if (s + 2 < 64) {
            AGG_WRITE(0, 0, (s + 2) * 32);
            asm volatile("s_waitcnt lgkmcnt(0)" ::: "memory");
            __builtin_amdgcn_s_barrier();
        }
    }
#undef AGG_LOAD
#undef AGG_WRITE
#undef AGG_COMPUTE

    int s_base = mt * 128 + wm * 64;
    int d_base = wn * 128;
    if (!a1z) {
#pragma unroll
        for (int mi = 0; mi < 4; ++mi)
#pragma unroll
            for (int ni = 0; ni < 8; ++ni) {
                int sb = s_base + mi * 16 + ((lane >> 4) << 2);
                int d = d_base + ni * 16 + (lane & 15);
#pragma unroll
                for (int r = 0; r < 4; ++r) {
                    size_t off = ((size_t)(b * S + sb + r)) * I + (size_t)h * HD + d;
                    hcomb[off] = f2bf(a1 * acc[mi][ni][r]);
                }
            }
    } else {
        // alpha == 0 fallback: h_gin = e1*h, read h from hhT (never taken in bench)
#pragma unroll
        for (int mi = 0; mi < 4; ++mi)
#pragma unroll
            for (int ni = 0; ni < 8; ++ni) {
                int sb = s_base + mi * 16 + ((lane >> 4) << 2);
                int d = d_base + ni * 16 + (lane & 15);
                size_t col = (size_t)h * HD + d;
                ushort4 hq = *(const ushort4*)(hhT + ((size_t)b * I + col) * S + sb);
#pragma unroll
                for (int r = 0; r < 4; ++r) {
                    size_t off = ((size_t)(b * S + sb + r)) * I + col;
                    hcomb[off] = f2bf(e1 * bf2f(((const unsigned short*)&hq)[r]));
                }
            }
    }
}

// ---------------- GEMM 3 v3: final projection, 6-buffer lookahead-4 ----------------
__global__ void __launch_bounds__(512, 2) gemm_out2(
    const unsigned short* __restrict__ hcomb, // 4096 x 8192
    const unsigned short* __restrict__ WdT,   // 2048 x 8192
    float* __restrict__ out)                  // 4096 x 2048
{
    const int K = 8192;
    __shared__ unsigned short LDS[6][12288];  // 144 KB: per buf A 16 KB + B 8 KB
    int bid = (int)blockIdx.x;
    int lb = (bid & 7) * 32 + (bid >> 3);     // bijective: 256 = 8 * 32
    int mt = lb >> 4, nt = lb & 15;           // mt-major chunks: A-panel L2 reuse per XCD
    int tid = threadIdx.x, lane = tid & 63, wave = tid >> 6;
    int wm = wave >> 1, wn = wave & 1;        // 4M x 2N waves, wave tile 64x64
    int l15 = lane & 15, l4 = lane >> 4;
    f32x4 acc[4][4] = {};

    int jl = (lane & 7) ^ (lane >> 3);
    int prowA = wave * 16 + (lane >> 3);
    int rowA0 = prowA + ((jl & 4) << 5);
    int ccA = (jl & 3) << 3;
    const unsigned short* srcA0 = hcomb + (size_t)(mt * 256 + rowA0) * K + ccA;
    const unsigned short* srcA1 = srcA0 + (size_t)8 * K;
    int prowB = tid >> 3;
    int jbl = (tid & 7) ^ (prowB & 7);
    int rowB0 = prowB + ((jbl & 4) << 4);
    int ccB = (jbl & 3) << 3;
    const unsigned short* srcB0 = WdT + (size_t)(nt * 128 + rowB0) * K + ccB;

    int cA0 = ((wm & 1) * 64 + l15) * 128 + (((((wm >> 1) << 2) + l4) ^ (l15 & 7)) << 4);
    int cB0 = l15 * 128 + ((((wn << 2) + l4) ^ (l15 & 7)) << 4);

#define OSTAGE(t_) do {                                                                  \
        char* dA = (char*)&LDS[(t_) % 6][0] + wave * 2048;                               \
        gload_lds16((const void*)(srcA0 + (size_t)(t_) * 32), (void*)dA);                \
        gload_lds16((const void*)(srcA1 + (size_t)(t_) * 32), (void*)(dA + 1024));       \
        char* dB = (char*)&LDS[(t_) % 6][8192] + wave * 1024;                            \
        gload_lds16((const void*)(srcB0 + (size_t)(t_) * 32), (void*)dB);                \
    } while (0)

    OSTAGE(0); OSTAGE(1); OSTAGE(2); OSTAGE(3);

    for (int t = 0; t < 256; ++t) {
        // lookahead-4 counted wait; tail drains 9 -> 6 -> 3 -> 0
        if (t + 3 < 256)      asm volatile("s_waitcnt vmcnt(9)" ::: "memory");
        else if (t + 2 < 256) asm volatile("s_waitcnt vmcnt(6)" ::: "memory");
        else if (t + 1 < 256) asm volatile("s_waitcnt vmcnt(3)" ::: "memory");
        else                  asm volatile("s_waitcnt vmcnt(0)" ::: "memory");
        __builtin_amdgcn_s_barrier();
        const char* Abase = (const char*)&LDS[t % 6][0];
        const char* Bbase = Abase + 16384;
        bool more = (t + 4) < 256;
        bf16x8 af[4], bf[4];
#pragma unroll
        for (int ni = 0; ni < 4; ++ni) bf[ni] = *(const bf16x8*)(Bbase + cB0 + ni * 2048);
        if (more) OSTAGE(t + 4);
#pragma unroll
        for (int mi = 0; mi < 4; ++mi) af[mi] = *(const bf16x8*)(Abase + cA0 + mi * 2048);
        __builtin_amdgcn_s_setprio(1);
#pragma unroll
        for (int mi = 0; mi < 4; ++mi)
#pragma unroll
            for (int ni = 0; ni < 4; ++ni)
                acc[mi][ni] = __builtin_amdgcn_mfma_f32_16x16x32_bf16(af[mi], bf[ni], acc[mi][ni], 0, 0, 0);
        __builtin_amdgcn_s_setprio(0);
    }
#undef OSTAGE

    int m_off = mt * 256 + wm * 64, n_off = nt * 128 + wn * 64;
#pragma unroll
    for (int mi = 0; mi < 4; ++mi)
#pragma unroll
        for (int ni = 0; ni < 4; ++ni) {
            int mbase = m_off + mi * 16 + l4 * 4;
            int n = n_off + ni * 16 + l15;
#pragma unroll
            for (int r = 0; r < 4; ++r)
                out[(size_t)(mbase + r) * 2048 + n] = acc[mi][ni][r];
        }
}

extern "C" void kernel_launch(void* const* d_in, const int* in_sizes, int n_in,
                              void* d_out, int out_size, void* d_ws, size_t ws_size,
                              hipStream_t stream) {
    const float* x     = (const float*)d_in[0];
    const float* adj   = (const float*)d_in[1];
    const float* Wg    = (const float*)d_in[2];
    const float* Wu    = (const float*)d_in[3];
    const float* Wd    = (const float*)d_in[4];
    const float* eps   = (const float*)d_in[5];
    const float* alpha = (const float*)d_in[6];
    float* out = (float*)d_out;

    unsigned short* ws    = (unsigned short*)d_ws;
    unsigned short* xb    = ws;                               // 4096*2048
    unsigned short* WgT   = xb + (size_t)4096 * 2048;         // 8192*2048
    unsigned short* WuT   = WgT + (size_t)8192 * 2048;        // 8192*2048
    unsigned short* WdT   = WuT + (size_t)8192 * 2048;        // 2048*8192
    unsigned short* hhT   = WdT + (size_t)2048 * 8192;        // 16384*2048
    unsigned short* hcomb = hhT + (size_t)16384 * 2048;       // 4096*8192
    unsigned short* gbuf  = hcomb;  // gate result overlays hcomb (dead before agg3 writes)

    conv_kernel<<<8192, 256, 0, stream>>>(x, xb);
    tconv_kernel<<<4096, 256, 0, stream>>>(Wg, WgT, 2048, 8192);
    tconv_kernel<<<4096, 256, 0, stream>>>(Wu, WuT, 2048, 8192);
    tconv_kernel<<<4096, 256, 0, stream>>>(Wd, WdT, 8192, 2048);
    gemm256<0><<<512, 512, 0, stream>>>(xb, WgT, nullptr, gbuf, nullptr);
    gemm256<1><<<512, 512, 0, stream>>>(xb, WuT, gbuf, nullptr, hhT);
    gemm_agg3<<<512, 512, 0, stream>>>(adj, hhT, eps, alpha, hcomb);
    gemm_out2<<<256, 512, 0, stream>>>(hcomb, WdT, out);
}